// Round 1
// 3106.026 us; speedup vs baseline: 1.3303x; 1.3303x over previous
//
#include <hip/hip_runtime.h>
#include <hip/hip_bf16.h>

typedef __hip_bfloat16 bf16;
typedef __attribute__((ext_vector_type(8))) short short8;
typedef __attribute__((ext_vector_type(4))) float f32x4;

#define NN 100000
#define NE 1600000

// ---------------- dtype detection ----------------
__global__ void detect_kernel(const unsigned int* __restrict__ x, int* __restrict__ flags) {
    __shared__ int s;
    if (threadIdx.x == 0) s = 0;
    __syncthreads();
    int c = 0;
    for (int j = 0; j < 4; ++j) {
        unsigned int w = x[threadIdx.x * 4 + j];
        unsigned int e = (w >> 7) & 0xFF;
        if (e >= 100 && e <= 141) c++;
    }
    atomicAdd(&s, c);
    __syncthreads();
    if (threadIdx.x == 0) flags[0] = (s > 128) ? 1 : 0;
}

// ---------------- input canonicalization ----------------
__global__ __launch_bounds__(256) void cvt_bf16_kernel(const void* __restrict__ in,
                                                       bf16* __restrict__ out, int n4,
                                                       const int* __restrict__ flagp) {
    int i = blockIdx.x * 256 + threadIdx.x;
    if (i >= n4) return;
    if (flagp[0]) {
        ((uint2*)out)[i] = ((const uint2*)in)[i];
    } else {
        float4 f = ((const float4*)in)[i];
        size_t o = (size_t)i * 4;
        out[o + 0] = __float2bfloat16(f.x);
        out[o + 1] = __float2bfloat16(f.y);
        out[o + 2] = __float2bfloat16(f.z);
        out[o + 3] = __float2bfloat16(f.w);
    }
}

// rows x sk (src) -> rows x dk (dst, zero-padded cols sk..dk). sk%4==0, dk%4==0.
__global__ __launch_bounds__(256) void cvt_pad_kernel(const void* __restrict__ in,
                                                      bf16* __restrict__ out,
                                                      int rows, int sk, int dk,
                                                      const int* __restrict__ flagp) {
    int i = blockIdx.x * 256 + threadIdx.x;
    int g4 = dk >> 2;
    if (i >= rows * g4) return;
    int row = i / g4;
    int c = (i - row * g4) * 4;
    uint2 w;
    w.x = 0u; w.y = 0u;
    if (c < sk) {
        if (flagp[0]) {
            w = *(const uint2*)((const char*)in + ((size_t)row * sk + c) * 2);
        } else {
            const float* f = (const float*)((const char*)in + ((size_t)row * sk + c) * 4);
            union { bf16 t[4]; uint2 u; } pk;
            pk.t[0] = __float2bfloat16(f[0]);
            pk.t[1] = __float2bfloat16(f[1]);
            pk.t[2] = __float2bfloat16(f[2]);
            pk.t[3] = __float2bfloat16(f[3]);
            w = pk.u;
        }
    }
    *(uint2*)((char*)out + ((size_t)row * dk + c) * 2) = w;
}

__global__ __launch_bounds__(256) void cvt_f32_kernel(const void* __restrict__ in,
                                                      float* __restrict__ out, int n,
                                                      const int* __restrict__ flagp) {
    int i = blockIdx.x * 256 + threadIdx.x;
    if (i >= n) return;
    if (flagp[0]) out[i] = __bfloat162float(((const bf16*)in)[i]);
    else out[i] = ((const float*)in)[i];
}

__global__ __launch_bounds__(256) void fill_kernel(bf16* __restrict__ out, long long n) {
    long long i = (long long)blockIdx.x * 256 + threadIdx.x;
    if (i < n) out[i] = __float2bfloat16(1000.0f);
}

// ---------------- CSR build ----------------

__global__ __launch_bounds__(256) void count_kernel(const int* __restrict__ dst,
                                                    int* __restrict__ cnt) {
    int e = blockIdx.x * 256 + threadIdx.x;
    if (e < NE) atomicAdd(&cnt[dst[e]], 1);
}

__global__ __launch_bounds__(1024) void scan_kernel(const int* __restrict__ cnt,
                                                    int* __restrict__ indptr,
                                                    int* __restrict__ cursor,
                                                    float* __restrict__ recip) {
    __shared__ int lds[1024];
    const int SEG = (NN + 1023) / 1024;  // 98
    int t = threadIdx.x;
    int base = t * SEG;
    int s = 0;
    for (int i = 0; i < SEG; ++i) {
        int idx = base + i;
        if (idx < NN) s += cnt[idx];
    }
    lds[t] = s;
    __syncthreads();
    for (int off = 1; off < 1024; off <<= 1) {
        int v = (t >= off) ? lds[t - off] : 0;
        __syncthreads();
        lds[t] += v;
        __syncthreads();
    }
    int run = lds[t] - s;  // exclusive prefix
    for (int i = 0; i < SEG; ++i) {
        int idx = base + i;
        if (idx < NN) {
            int c = cnt[idx];
            indptr[idx] = run;
            cursor[idx] = run;
            recip[idx] = 1.0f / (float)(c > 1 ? c : 1);
            run += c;
        }
    }
    if (t == 1023) indptr[NN] = lds[1023];
}

__global__ __launch_bounds__(256) void scatter_kernel(const int* __restrict__ src,
                                                      const int* __restrict__ dst,
                                                      int* __restrict__ cursor,
                                                      int* __restrict__ csr) {
    int e = blockIdx.x * 256 + threadIdx.x;
    if (e < NE) {
        int d = dst[e];
        int p = atomicAdd(&cursor[d], 1);
        csr[p] = src[e];
    }
}

// ---------------- aggregation (pull over CSR) ----------------
template <int ADD>
__global__ __launch_bounds__(256) void agg_kernel(const bf16* __restrict__ u,
                                                  const int* __restrict__ indptr,
                                                  const int* __restrict__ csr,
                                                  const float* __restrict__ recip,
                                                  int ld,  // log2(D)
                                                  bf16* __restrict__ out) {
    int node = blockIdx.x * (256 >> ld) + (threadIdx.x >> ld);
    int c = threadIdx.x & ((1 << ld) - 1);
    if (node >= NN) return;
    int j0 = indptr[node], j1 = indptr[node + 1];
    float acc = 0.f;
    for (int j = j0; j < j1; ++j) {
        int sIdx = csr[j];
        acc += __bfloat162float(u[((size_t)sIdx << ld) + c]);
    }
    float v = acc * recip[node];
    size_t o = ((size_t)node << ld) + c;
    if (ADD) v += __bfloat162float(out[o]);
    out[o] = __float2bfloat16(v);
}

// ---------------- bf16 MFMA GEMM:  out = A1@W1^T (+ A2@W2^T) (+ bias) ----------------
// m97-class structure: 256x64 block tile, BK=64, 256 threads (4 waves).
// Wave wv owns rows [64*wv, 64*wv+64) x all 64 cols: 4x4 frags of 16x16x32 MFMA
// => 32 MFMA per wave per K-step between one barrier pair.
// Staging: global_load_lds dwordx4 (16B/lane), LDS linear dest; XOR swizzle
// (byte ^= (row&7)<<4) applied to the GLOBAL source column and to the ds_read
// address (both-sides involution, guide rule #21) -> conflict-free b128 reads.
// K must be a multiple of 64 (layer-1 K=196 is zero-padded to 256 at cvt time).

__device__ __forceinline__ void gld_lds16(const void* g, void* l) {
    __builtin_amdgcn_global_load_lds(
        (const __attribute__((address_space(1))) unsigned int*)g,
        (__attribute__((address_space(3))) unsigned int*)l, 16, 0, 0);
}

__global__ __launch_bounds__(256) void gemm_kernel(
    const bf16* __restrict__ A1, const bf16* __restrict__ W1, int K1,
    const bf16* __restrict__ A2, const bf16* __restrict__ W2, int K2,
    const float* __restrict__ bias,
    bf16* __restrict__ outB, void* __restrict__ outFinal,
    const int* __restrict__ flagp,
    int M, int N) {
    __shared__ alignas(16) char sA[256 * 128];  // 256 rows x 64 bf16 (swizzled)
    __shared__ alignas(16) char sW[64 * 128];   // 64 rows x 64 bf16 (swizzled)

    const int tid = threadIdx.x;
    const int lane = tid & 63, wv = tid >> 6;
    const int lrow = lane & 15, lq = lane >> 4;
    const int n0 = blockIdx.x * 64;   // N-tile (x fastest: co-resident blocks share A panel)
    const int m0 = blockIdx.y * 256;  // M-tile
    const int isbf = flagp[0];

    f32x4 acc[4][4];
#pragma unroll
    for (int a = 0; a < 4; ++a)
#pragma unroll
        for (int b = 0; b < 4; ++b) acc[a][b] = (f32x4){0.f, 0.f, 0.f, 0.f};

    const int sr = tid >> 3;          // staging row sub-index 0..31
    const int scb = (tid & 7) << 4;   // staging col byte 0..112 (16B chunks)

#pragma unroll 1
    for (int seg = 0; seg < 2; ++seg) {
        const bf16* Ap = seg ? A2 : A1;
        const bf16* Wp = seg ? W2 : W1;
        const int K = seg ? K2 : K1;
        if (K == 0) continue;
#pragma unroll 1
        for (int k0 = 0; k0 < K; k0 += 64) {
            __syncthreads();  // previous compute done before overwrite
            // stage A tile: 256 rows x 128B, 8 x 16B per thread
#pragma unroll
            for (int i = 0; i < 8; ++i) {
                int row = i * 32 + sr;
                int gr = m0 + row;
                if (gr >= M) gr = M - 1;  // clamp tail (epilogue guards writes)
                const char* g = (const char*)Ap + ((size_t)gr * K + k0) * 2 +
                                (scb ^ ((row & 7) << 4));
                gld_lds16(g, sA + row * 128 + scb);
            }
            // stage W tile: 64 rows x 128B, 2 x 16B per thread (N multiple of 64)
#pragma unroll
            for (int i = 0; i < 2; ++i) {
                int row = i * 32 + sr;
                const char* g = (const char*)Wp + ((size_t)(n0 + row) * K + k0) * 2 +
                                (scb ^ ((row & 7) << 4));
                gld_lds16(g, sW + row * 128 + scb);
            }
            __syncthreads();  // drains vmcnt(0) then barrier
#pragma unroll
            for (int kh = 0; kh < 2; ++kh) {
                short8 a[4], b[4];
                const int cb = kh * 64 + lq * 16;
#pragma unroll
                for (int mi = 0; mi < 4; ++mi) {
                    int row = wv * 64 + mi * 16 + lrow;
                    a[mi] = *(const short8*)(sA + row * 128 + (cb ^ ((row & 7) << 4)));
                }
#pragma unroll
                for (int ni = 0; ni < 4; ++ni) {
                    int row = ni * 16 + lrow;
                    b[ni] = *(const short8*)(sW + row * 128 + (cb ^ ((row & 7) << 4)));
                }
#pragma unroll
                for (int mi = 0; mi < 4; ++mi)
#pragma unroll
                    for (int ni = 0; ni < 4; ++ni)
                        acc[mi][ni] = __builtin_amdgcn_mfma_f32_16x16x32_bf16(
                            a[mi], b[ni], acc[mi][ni], 0, 0, 0);
            }
        }
    }

    // epilogue: C/D layout col=lane&15, row=lq*4+reg
#pragma unroll
    for (int ni = 0; ni < 4; ++ni) {
        int gcol = n0 + ni * 16 + lrow;
        float bv = bias ? bias[gcol] : 0.f;
#pragma unroll
        for (int mi = 0; mi < 4; ++mi) {
#pragma unroll
            for (int r = 0; r < 4; ++r) {
                int grow = m0 + wv * 64 + mi * 16 + lq * 4 + r;
                if (grow < M) {
                    size_t o = (size_t)grow * N + gcol;
                    float v = acc[mi][ni][r] + bv;
                    if (outFinal) {
                        if (isbf) ((bf16*)outFinal)[o] = __float2bfloat16(v);
                        else ((float*)outFinal)[o] = v;
                    } else {
                        outB[o] = __float2bfloat16(v);
                    }
                }
            }
        }
    }
}

// ---------------- BatchNorm ----------------

__global__ __launch_bounds__(256) void bn_stats_kernel(const bf16* __restrict__ C,
                                                       int ldN,
                                                       float* __restrict__ stats) {
    int N = 1 << ldN;
    int tid = threadIdx.x;
    int c = tid & (N - 1);
    int rsub = tid >> ldN;
    int rstep = 256 >> ldN;
    int r0 = blockIdx.x * 64;
    float s = 0.f, q = 0.f;
    for (int r = r0 + rsub; r < r0 + 64; r += rstep) {
        if (r < NN) {
            float v = __bfloat162float(C[(size_t)r * N + c]);
            s += v;
            q += v * v;
        }
    }
    __shared__ float ls[256], lq[256];
    ls[tid] = s;
    lq[tid] = q;
    __syncthreads();
    for (int half = rstep >> 1; half > 0; half >>= 1) {
        if (rsub < half) {
            ls[tid] += ls[tid + half * N];
            lq[tid] += lq[tid + half * N];
        }
        __syncthreads();
    }
    if (rsub == 0) {
        atomicAdd(&stats[c], ls[tid]);
        atomicAdd(&stats[N + c], lq[tid]);
    }
}

__global__ __launch_bounds__(256) void bn_finalize_kernel(const float* __restrict__ stats,
                                                          const float* __restrict__ g,
                                                          const float* __restrict__ be,
                                                          int N,
                                                          float* __restrict__ scale,
                                                          float* __restrict__ shift) {
    int c = threadIdx.x;
    if (c >= N) return;
    float mean = stats[c] * (1.0f / NN);
    float var = stats[N + c] * (1.0f / NN) - mean * mean;
    var = fmaxf(var, 0.f);
    float sc = g[c] * rsqrtf(var + 1e-5f);
    scale[c] = sc;
    shift[c] = be[c] - mean * sc;
}

__global__ __launch_bounds__(256) void bn_apply_kernel(const bf16* __restrict__ C,
                                                       const float* __restrict__ scale,
                                                       const float* __restrict__ shift,
                                                       int mask,  // N-1
                                                       bf16* __restrict__ act,
                                                       long long total) {
    long long i = (long long)blockIdx.x * 256 + threadIdx.x;
    if (i < total) {
        int c = (int)(i & mask);
        float v = __bfloat162float(C[i]) * scale[c] + shift[c];
        act[i] = __float2bfloat16(v > 0.f ? v : 0.f);
    }
}

// ---------------- host launch ----------------

extern "C" void kernel_launch(void* const* d_in, const int* in_sizes, int n_in,
                              void* d_out, int out_size, void* d_ws, size_t ws_size,
                              hipStream_t stream) {
    const void* x_raw = d_in[0];
    const int* ei = (const int*)d_in[1];
    const int* src = ei;
    const int* dst = ei + NE;

    char* w = (char*)d_ws;
    size_t off = 0;
    auto alloc = [&](size_t bytes) {
        void* p = w + off;
        off = (off + bytes + 255) & ~(size_t)255;
        return p;
    };
    int* flags = (int*)alloc(256);
    int* cnt = (int*)alloc((size_t)NN * 4);
    int* indptr = (int*)alloc((size_t)(NN + 1) * 4);
    int* cursor = (int*)alloc((size_t)NN * 4);
    float* recip = (float*)alloc((size_t)NN * 4);
    int* csr = (int*)alloc((size_t)NE * 4);
    // canonical bf16 weights (K padded to mult of 64) + fp32 bias/gamma/beta
    const int KDIM[5] = {196, 64, 128, 256, 256};   // source K
    const int KPAD[5] = {256, 64, 128, 256, 256};   // padded K (row stride)
    const int NDIM[5] = {64, 128, 256, 256, 576};
    bf16 *Wlb[5], *Wrb[5];
    float *bf_[5], *gf[4], *bef[4];
    for (int i = 0; i < 5; ++i) {
        Wlb[i] = (bf16*)alloc((size_t)KPAD[i] * NDIM[i] * 2);
        Wrb[i] = (bf16*)alloc((size_t)KPAD[i] * NDIM[i] * 2);
        bf_[i] = (float*)alloc((size_t)NDIM[i] * 4);
    }
    for (int i = 0; i < 4; ++i) {
        gf[i] = (float*)alloc((size_t)NDIM[i] * 4);
        bef[i] = (float*)alloc((size_t)NDIM[i] * 4);
    }
    float* stats = (float*)alloc(1408 * 4);
    float* scale = (float*)alloc(256 * 4);
    float* shift = (float*)alloc(256 * 4);
    float *s1 = stats, *s2 = stats + 128, *s3 = stats + 384, *s4 = stats + 896;
    // big slots
    bf16* aggb = (bf16*)alloc((size_t)NN * 256 * 2);  // also holds xb (NN x 256 padded)
    bf16* S1 = (bf16*)alloc((size_t)NN * 256 * 2);
    bf16* S2 = (bf16*)alloc((size_t)NN * 256 * 2);
    bf16* xb = aggb;  // NN*256 bf16 = 51.2 MB, exactly fills aggb slot
    bf16* u1 = S2;    // NN*64 bf16, layer-1 scratch in S2

    if (off > ws_size) {
        long long n = (long long)NN * 576;
        fill_kernel<<<(int)((n + 255) / 256), 256, 0, stream>>>((bf16*)d_out, n);
        return;
    }

    hipMemsetAsync(cnt, 0, (size_t)NN * 4, stream);
    hipMemsetAsync(stats, 0, 1408 * 4, stream);

    detect_kernel<<<1, 64, 0, stream>>>((const unsigned int*)x_raw, flags);

    // canonicalize inputs to bf16 (K-padded) / fp32
    {
        int totx = NN * (KPAD[0] >> 2);
        cvt_pad_kernel<<<(totx + 255) / 256, 256, 0, stream>>>(x_raw, xb, NN, 196, 256, flags);
        for (int i = 0; i < 5; ++i) {
            if (KPAD[i] != KDIM[i]) {
                int tot = NDIM[i] * (KPAD[i] >> 2);
                cvt_pad_kernel<<<(tot + 255) / 256, 256, 0, stream>>>(
                    d_in[2 + 3 * i], Wlb[i], NDIM[i], KDIM[i], KPAD[i], flags);
                cvt_pad_kernel<<<(tot + 255) / 256, 256, 0, stream>>>(
                    d_in[3 + 3 * i], Wrb[i], NDIM[i], KDIM[i], KPAD[i], flags);
            } else {
                int nw4 = KDIM[i] * NDIM[i] / 4;
                cvt_bf16_kernel<<<(nw4 + 255) / 256, 256, 0, stream>>>(d_in[2 + 3 * i], Wlb[i], nw4, flags);
                cvt_bf16_kernel<<<(nw4 + 255) / 256, 256, 0, stream>>>(d_in[3 + 3 * i], Wrb[i], nw4, flags);
            }
            cvt_f32_kernel<<<(NDIM[i] + 255) / 256, 256, 0, stream>>>(d_in[4 + 3 * i], bf_[i], NDIM[i], flags);
        }
        for (int i = 0; i < 4; ++i) {
            cvt_f32_kernel<<<(NDIM[i] + 255) / 256, 256, 0, stream>>>(d_in[17 + 2 * i], gf[i], NDIM[i], flags);
            cvt_f32_kernel<<<(NDIM[i] + 255) / 256, 256, 0, stream>>>(d_in[18 + 2 * i], bef[i], NDIM[i], flags);
        }
    }

    count_kernel<<<(NE + 255) / 256, 256, 0, stream>>>(dst, cnt);
    scan_kernel<<<1, 1024, 0, stream>>>(cnt, indptr, cursor, recip);
    scatter_kernel<<<(NE + 255) / 256, 256, 0, stream>>>(src, dst, cursor, csr);

    const int GM = (NN + 63) / 64;     // bn_stats grid (64 rows/block)
    const int GY = (NN + 255) / 256;   // gemm M-tiles (391)

    // ---- Layer 1: 196(pad 256) -> 64 (aggregate AFTER lin_l)
    gemm_kernel<<<dim3(1, GY), 256, 0, stream>>>(xb, Wlb[0], 256, nullptr, nullptr, 0,
                                                 nullptr, u1, nullptr, flags, NN, 64);
    gemm_kernel<<<dim3(1, GY), 256, 0, stream>>>(xb, Wrb[0], 256, nullptr, nullptr, 0,
                                                 bf_[0], S1, nullptr, flags, NN, 64);
    agg_kernel<1><<<NN / 4, 256, 0, stream>>>(u1, indptr, csr, recip, 6, S1);
    bn_stats_kernel<<<GM, 256, 0, stream>>>(S1, 6, s1);
    bn_finalize_kernel<<<1, 256, 0, stream>>>(s1, gf[0], bef[0], 64, scale, shift);
    bn_apply_kernel<<<(NN * 64 + 255) / 256, 256, 0, stream>>>(S1, scale, shift, 63, S1,
                                                               (long long)NN * 64);

    // ---- Layer 2: 64 -> 128  (act1 in S1)
    agg_kernel<0><<<NN / 4, 256, 0, stream>>>(S1, indptr, csr, recip, 6, aggb);
    gemm_kernel<<<dim3(2, GY), 256, 0, stream>>>(aggb, Wlb[1], 64, S1, Wrb[1], 64,
                                                 bf_[1], S2, nullptr, flags, NN, 128);
    bn_stats_kernel<<<GM, 256, 0, stream>>>(S2, 7, s2);
    bn_finalize_kernel<<<1, 256, 0, stream>>>(s2, gf[1], bef[1], 128, scale, shift);
    bn_apply_kernel<<<(NN * 128 + 255) / 256, 256, 0, stream>>>(S2, scale, shift, 127, S2,
                                                                (long long)NN * 128);

    // ---- Layer 3: 128 -> 256  (act2 in S2)
    agg_kernel<0><<<NN / 2, 256, 0, stream>>>(S2, indptr, csr, recip, 7, aggb);
    gemm_kernel<<<dim3(4, GY), 256, 0, stream>>>(aggb, Wlb[2], 128, S2, Wrb[2], 128,
                                                 bf_[2], S1, nullptr, flags, NN, 256);
    bn_stats_kernel<<<GM, 256, 0, stream>>>(S1, 8, s3);
    bn_finalize_kernel<<<1, 256, 0, stream>>>(s3, gf[2], bef[2], 256, scale, shift);
    bn_apply_kernel<<<(NN * 256 + 255) / 256, 256, 0, stream>>>(S1, scale, shift, 255, S1,
                                                                (long long)NN * 256);

    // ---- Layer 4: 256 -> 256  (act3 in S1)
    agg_kernel<0><<<NN, 256, 0, stream>>>(S1, indptr, csr, recip, 8, aggb);
    gemm_kernel<<<dim3(4, GY), 256, 0, stream>>>(aggb, Wlb[3], 256, S1, Wrb[3], 256,
                                                 bf_[3], S2, nullptr, flags, NN, 256);
    bn_stats_kernel<<<GM, 256, 0, stream>>>(S2, 8, s4);
    bn_finalize_kernel<<<1, 256, 0, stream>>>(s4, gf[3], bef[3], 256, scale, shift);
    bn_apply_kernel<<<(NN * 256 + 255) / 256, 256, 0, stream>>>(S2, scale, shift, 255, S2,
                                                                (long long)NN * 256);

    // ---- Layer 5: 256 -> 576, no BN/ReLU, write d_out (bf16 or fp32 per flag)
    agg_kernel<0><<<NN, 256, 0, stream>>>(S2, indptr, csr, recip, 8, aggb);
    gemm_kernel<<<dim3(9, GY), 256, 0, stream>>>(aggb, Wlb[4], 256, S2, Wrb[4], 256,
                                                 bf_[4], nullptr, d_out, flags, NN, 576);
}

// Round 2
// 1763.849 us; speedup vs baseline: 2.3426x; 1.7609x over previous
//
#include <hip/hip_runtime.h>
#include <hip/hip_bf16.h>

typedef __hip_bfloat16 bf16;
typedef __attribute__((ext_vector_type(8))) short short8;
typedef __attribute__((ext_vector_type(4))) float f32x4;

#define NN 100000
#define NE 1600000

__device__ __forceinline__ float bf2f(short s) {
    return __uint_as_float(((unsigned int)(unsigned short)s) << 16);
}
__device__ __forceinline__ short f2bf(float f) {
    union { bf16 b; short s; } u;
    u.b = __float2bfloat16(f);
    return u.s;
}

// ---------------- dtype detection ----------------
__global__ void detect_kernel(const unsigned int* __restrict__ x, int* __restrict__ flags) {
    __shared__ int s;
    if (threadIdx.x == 0) s = 0;
    __syncthreads();
    int c = 0;
    for (int j = 0; j < 4; ++j) {
        unsigned int w = x[threadIdx.x * 4 + j];
        unsigned int e = (w >> 7) & 0xFF;
        if (e >= 100 && e <= 141) c++;
    }
    atomicAdd(&s, c);
    __syncthreads();
    if (threadIdx.x == 0) flags[0] = (s > 128) ? 1 : 0;
}

// ---------------- input canonicalization ----------------
__global__ __launch_bounds__(256) void cvt_bf16_kernel(const void* __restrict__ in,
                                                       bf16* __restrict__ out, int n4,
                                                       const int* __restrict__ flagp) {
    int i = blockIdx.x * 256 + threadIdx.x;
    if (i >= n4) return;
    if (flagp[0]) {
        ((uint2*)out)[i] = ((const uint2*)in)[i];
    } else {
        float4 f = ((const float4*)in)[i];
        size_t o = (size_t)i * 4;
        out[o + 0] = __float2bfloat16(f.x);
        out[o + 1] = __float2bfloat16(f.y);
        out[o + 2] = __float2bfloat16(f.z);
        out[o + 3] = __float2bfloat16(f.w);
    }
}

// rows x sk (src) -> rows x dk (dst, zero-padded cols sk..dk). sk%4==0, dk%4==0.
__global__ __launch_bounds__(256) void cvt_pad_kernel(const void* __restrict__ in,
                                                      bf16* __restrict__ out,
                                                      int rows, int sk, int dk,
                                                      const int* __restrict__ flagp) {
    int i = blockIdx.x * 256 + threadIdx.x;
    int g4 = dk >> 2;
    if (i >= rows * g4) return;
    int row = i / g4;
    int c = (i - row * g4) * 4;
    uint2 w;
    w.x = 0u; w.y = 0u;
    if (c < sk) {
        if (flagp[0]) {
            w = *(const uint2*)((const char*)in + ((size_t)row * sk + c) * 2);
        } else {
            const float* f = (const float*)((const char*)in + ((size_t)row * sk + c) * 4);
            union { bf16 t[4]; uint2 u; } pk;
            pk.t[0] = __float2bfloat16(f[0]);
            pk.t[1] = __float2bfloat16(f[1]);
            pk.t[2] = __float2bfloat16(f[2]);
            pk.t[3] = __float2bfloat16(f[3]);
            w = pk.u;
        }
    }
    *(uint2*)((char*)out + ((size_t)row * dk + c) * 2) = w;
}

__global__ __launch_bounds__(256) void cvt_f32_kernel(const void* __restrict__ in,
                                                      float* __restrict__ out, int n,
                                                      const int* __restrict__ flagp) {
    int i = blockIdx.x * 256 + threadIdx.x;
    if (i >= n) return;
    if (flagp[0]) out[i] = __bfloat162float(((const bf16*)in)[i]);
    else out[i] = ((const float*)in)[i];
}

__global__ __launch_bounds__(256) void fill_kernel(bf16* __restrict__ out, long long n) {
    long long i = (long long)blockIdx.x * 256 + threadIdx.x;
    if (i < n) out[i] = __float2bfloat16(1000.0f);
}

// ---------------- CSR build ----------------

__global__ __launch_bounds__(256) void count_kernel(const int* __restrict__ dst,
                                                    int* __restrict__ cnt) {
    int e = blockIdx.x * 256 + threadIdx.x;
    if (e < NE) atomicAdd(&cnt[dst[e]], 1);
}

__global__ __launch_bounds__(1024) void scan_kernel(const int* __restrict__ cnt,
                                                    int* __restrict__ indptr,
                                                    int* __restrict__ cursor,
                                                    float* __restrict__ recip) {
    __shared__ int lds[1024];
    const int SEG = (NN + 1023) / 1024;  // 98
    int t = threadIdx.x;
    int base = t * SEG;
    int s = 0;
    for (int i = 0; i < SEG; ++i) {
        int idx = base + i;
        if (idx < NN) s += cnt[idx];
    }
    lds[t] = s;
    __syncthreads();
    for (int off = 1; off < 1024; off <<= 1) {
        int v = (t >= off) ? lds[t - off] : 0;
        __syncthreads();
        lds[t] += v;
        __syncthreads();
    }
    int run = lds[t] - s;  // exclusive prefix
    for (int i = 0; i < SEG; ++i) {
        int idx = base + i;
        if (idx < NN) {
            int c = cnt[idx];
            indptr[idx] = run;
            cursor[idx] = run;
            recip[idx] = 1.0f / (float)(c > 1 ? c : 1);
            run += c;
        }
    }
    if (t == 1023) indptr[NN] = lds[1023];
}

__global__ __launch_bounds__(256) void scatter_kernel(const int* __restrict__ src,
                                                      const int* __restrict__ dst,
                                                      int* __restrict__ cursor,
                                                      int* __restrict__ csr) {
    int e = blockIdx.x * 256 + threadIdx.x;
    if (e < NE) {
        int d = dst[e];
        int p = atomicAdd(&cursor[d], 1);
        csr[p] = src[e];
    }
}

// ---------------- aggregation (pull over CSR), vectorized 16B/lane ----------------
// D channels; each thread owns 8 contiguous channels (one dwordx4 per neighbor).
// Neighbor loop unrolled x4 -> 4 independent 16B gathers in flight per lane.
template <int D, int ADD>
__global__ __launch_bounds__(256) void aggv_kernel(const bf16* __restrict__ u,
                                                   const int* __restrict__ indptr,
                                                   const int* __restrict__ csr,
                                                   const float* __restrict__ recip,
                                                   bf16* __restrict__ out) {
    constexpr int TPR = D / 8;       // threads per node row
    constexpr int NPB = 256 / TPR;   // nodes per block
    const int tid = threadIdx.x;
    const int node = blockIdx.x * NPB + tid / TPR;
    if (node >= NN) return;
    const int c0 = (tid % TPR) * 8;
    const short* ub = (const short*)u + c0;
    const int j0 = indptr[node], j1 = indptr[node + 1];
    float acc[8];
#pragma unroll
    for (int t = 0; t < 8; ++t) acc[t] = 0.f;
    int j = j0;
    for (; j + 3 < j1; j += 4) {
        int s0 = csr[j], s1 = csr[j + 1], s2 = csr[j + 2], s3 = csr[j + 3];
        short8 v0 = *(const short8*)(ub + (size_t)s0 * D);
        short8 v1 = *(const short8*)(ub + (size_t)s1 * D);
        short8 v2 = *(const short8*)(ub + (size_t)s2 * D);
        short8 v3 = *(const short8*)(ub + (size_t)s3 * D);
#pragma unroll
        for (int t = 0; t < 8; ++t)
            acc[t] += (bf2f(v0[t]) + bf2f(v1[t])) + (bf2f(v2[t]) + bf2f(v3[t]));
    }
    for (; j < j1; ++j) {
        short8 v0 = *(const short8*)(ub + (size_t)csr[j] * D);
#pragma unroll
        for (int t = 0; t < 8; ++t) acc[t] += bf2f(v0[t]);
    }
    const float r = recip[node];
    size_t o = (size_t)node * D + c0;
    short8 w;
    if (ADD) {
        short8 prev = *(const short8*)((const short*)out + o);
#pragma unroll
        for (int t = 0; t < 8; ++t) w[t] = f2bf(acc[t] * r + bf2f(prev[t]));
    } else {
#pragma unroll
        for (int t = 0; t < 8; ++t) w[t] = f2bf(acc[t] * r);
    }
    *(short8*)((short*)out + o) = w;
}

// ---------------- bf16 MFMA GEMM:  out = A1@W1^T (+ A2@W2^T) (+ bias) ----------------
// 256x64 block tile, BK=64, 4 waves each owning 64x64 (4x4 frags, 32 MFMA/K-step).
// global_load_lds dwordx4 staging, linear LDS dest; XOR swizzle applied to the
// GLOBAL source column and to the ds_read address (both-sides involution).
// Optional fused BN stats: per-column sum/sumsq reduced per-wave then atomicAdd.
// K must be a multiple of 64 (layer-1 K=196 zero-padded to 256 at cvt time).

__device__ __forceinline__ void gld_lds16(const void* g, void* l) {
    __builtin_amdgcn_global_load_lds(
        (const __attribute__((address_space(1))) unsigned int*)g,
        (__attribute__((address_space(3))) unsigned int*)l, 16, 0, 0);
}

__global__ __launch_bounds__(256) void gemm_kernel(
    const bf16* __restrict__ A1, const bf16* __restrict__ W1, int K1,
    const bf16* __restrict__ A2, const bf16* __restrict__ W2, int K2,
    const float* __restrict__ bias,
    bf16* __restrict__ outB, void* __restrict__ outFinal,
    float* __restrict__ statp,
    const int* __restrict__ flagp,
    int M, int N) {
    __shared__ alignas(16) char sA[256 * 128];  // 256 rows x 64 bf16 (swizzled)
    __shared__ alignas(16) char sW[64 * 128];   // 64 rows x 64 bf16 (swizzled)

    const int tid = threadIdx.x;
    const int lane = tid & 63, wv = tid >> 6;
    const int lrow = lane & 15, lq = lane >> 4;
    const int n0 = blockIdx.x * 64;
    const int m0 = blockIdx.y * 256;
    const int isbf = flagp[0];

    f32x4 acc[4][4];
#pragma unroll
    for (int a = 0; a < 4; ++a)
#pragma unroll
        for (int b = 0; b < 4; ++b) acc[a][b] = (f32x4){0.f, 0.f, 0.f, 0.f};

    const int sr = tid >> 3;
    const int scb = (tid & 7) << 4;

#pragma unroll 1
    for (int seg = 0; seg < 2; ++seg) {
        const bf16* Ap = seg ? A2 : A1;
        const bf16* Wp = seg ? W2 : W1;
        const int K = seg ? K2 : K1;
        if (K == 0) continue;
#pragma unroll 1
        for (int k0 = 0; k0 < K; k0 += 64) {
            __syncthreads();
#pragma unroll
            for (int i = 0; i < 8; ++i) {
                int row = i * 32 + sr;
                int gr = m0 + row;
                if (gr >= M) gr = M - 1;  // clamp tail (epilogue guards writes)
                const char* g = (const char*)Ap + ((size_t)gr * K + k0) * 2 +
                                (scb ^ ((row & 7) << 4));
                gld_lds16(g, sA + row * 128 + scb);
            }
#pragma unroll
            for (int i = 0; i < 2; ++i) {
                int row = i * 32 + sr;
                const char* g = (const char*)Wp + ((size_t)(n0 + row) * K + k0) * 2 +
                                (scb ^ ((row & 7) << 4));
                gld_lds16(g, sW + row * 128 + scb);
            }
            __syncthreads();
#pragma unroll
            for (int kh = 0; kh < 2; ++kh) {
                short8 a[4], b[4];
                const int cb = kh * 64 + lq * 16;
#pragma unroll
                for (int mi = 0; mi < 4; ++mi) {
                    int row = wv * 64 + mi * 16 + lrow;
                    a[mi] = *(const short8*)(sA + row * 128 + (cb ^ ((row & 7) << 4)));
                }
#pragma unroll
                for (int ni = 0; ni < 4; ++ni) {
                    int row = ni * 16 + lrow;
                    b[ni] = *(const short8*)(sW + row * 128 + (cb ^ ((row & 7) << 4)));
                }
#pragma unroll
                for (int mi = 0; mi < 4; ++mi)
#pragma unroll
                    for (int ni = 0; ni < 4; ++ni)
                        acc[mi][ni] = __builtin_amdgcn_mfma_f32_16x16x32_bf16(
                            a[mi], b[ni], acc[mi][ni], 0, 0, 0);
            }
        }
    }

    // epilogue: C/D layout col=lane&15, row=lq*4+reg; fused BN column stats
#pragma unroll
    for (int ni = 0; ni < 4; ++ni) {
        int gcol = n0 + ni * 16 + lrow;
        float bv = bias ? bias[gcol] : 0.f;
        float s = 0.f, q = 0.f;
#pragma unroll
        for (int mi = 0; mi < 4; ++mi) {
#pragma unroll
            for (int r = 0; r < 4; ++r) {
                int grow = m0 + wv * 64 + mi * 16 + lq * 4 + r;
                if (grow < M) {
                    size_t o = (size_t)grow * N + gcol;
                    float v = acc[mi][ni][r] + bv;
                    s += v;
                    q += v * v;
                    if (outFinal) {
                        if (isbf) ((bf16*)outFinal)[o] = __float2bfloat16(v);
                        else ((float*)outFinal)[o] = v;
                    } else {
                        outB[o] = __float2bfloat16(v);
                    }
                }
            }
        }
        if (statp) {
            s += __shfl_xor(s, 16, 64);
            s += __shfl_xor(s, 32, 64);
            q += __shfl_xor(q, 16, 64);
            q += __shfl_xor(q, 32, 64);
            if (lq == 0) {
                atomicAdd(&statp[gcol], s);
                atomicAdd(&statp[N + gcol], q);
            }
        }
    }
}

// ---------------- BatchNorm ----------------

__global__ __launch_bounds__(256) void bn_stats_kernel(const bf16* __restrict__ C,
                                                       int ldN,
                                                       float* __restrict__ stats) {
    int N = 1 << ldN;
    int tid = threadIdx.x;
    int c = tid & (N - 1);
    int rsub = tid >> ldN;
    int rstep = 256 >> ldN;
    int r0 = blockIdx.x * 64;
    float s = 0.f, q = 0.f;
    for (int r = r0 + rsub; r < r0 + 64; r += rstep) {
        if (r < NN) {
            float v = __bfloat162float(C[(size_t)r * N + c]);
            s += v;
            q += v * v;
        }
    }
    __shared__ float ls[256], lq[256];
    ls[tid] = s;
    lq[tid] = q;
    __syncthreads();
    for (int half = rstep >> 1; half > 0; half >>= 1) {
        if (rsub < half) {
            ls[tid] += ls[tid + half * N];
            lq[tid] += lq[tid + half * N];
        }
        __syncthreads();
    }
    if (rsub == 0) {
        atomicAdd(&stats[c], ls[tid]);
        atomicAdd(&stats[N + c], lq[tid]);
    }
}

__global__ __launch_bounds__(256) void bn_finalize_kernel(const float* __restrict__ stats,
                                                          const float* __restrict__ g,
                                                          const float* __restrict__ be,
                                                          int N,
                                                          float* __restrict__ scale,
                                                          float* __restrict__ shift) {
    int c = threadIdx.x;
    if (c >= N) return;
    float mean = stats[c] * (1.0f / NN);
    float var = stats[N + c] * (1.0f / NN) - mean * mean;
    var = fmaxf(var, 0.f);
    float sc = g[c] * rsqrtf(var + 1e-5f);
    scale[c] = sc;
    shift[c] = be[c] - mean * sc;
}

// in-place ok; 8 bf16 (16B) per thread
__global__ __launch_bounds__(256) void bn_apply_kernel(const bf16* __restrict__ C,
                                                       const float* __restrict__ scale,
                                                       const float* __restrict__ shift,
                                                       int mask,  // N-1 (N>=64)
                                                       bf16* __restrict__ act,
                                                       long long total8) {
    long long i = (long long)blockIdx.x * 256 + threadIdx.x;
    if (i >= total8) return;
    int c0 = (int)((i * 8) & mask);
    short8 v = ((const short8*)C)[i];
    float4 sc0 = *(const float4*)&scale[c0];
    float4 sc1 = *(const float4*)&scale[c0 + 4];
    float4 sh0 = *(const float4*)&shift[c0];
    float4 sh1 = *(const float4*)&shift[c0 + 4];
    short8 w;
#pragma unroll
    for (int t = 0; t < 4; ++t) {
        float x = bf2f(v[t]) * ((const float*)&sc0)[t] + ((const float*)&sh0)[t];
        w[t] = f2bf(x > 0.f ? x : 0.f);
    }
#pragma unroll
    for (int t = 0; t < 4; ++t) {
        float x = bf2f(v[t + 4]) * ((const float*)&sc1)[t] + ((const float*)&sh1)[t];
        w[t + 4] = f2bf(x > 0.f ? x : 0.f);
    }
    ((short8*)act)[i] = w;
}

// ---------------- host launch ----------------

extern "C" void kernel_launch(void* const* d_in, const int* in_sizes, int n_in,
                              void* d_out, int out_size, void* d_ws, size_t ws_size,
                              hipStream_t stream) {
    const void* x_raw = d_in[0];
    const int* ei = (const int*)d_in[1];
    const int* src = ei;
    const int* dst = ei + NE;

    char* w = (char*)d_ws;
    size_t off = 0;
    auto alloc = [&](size_t bytes) {
        void* p = w + off;
        off = (off + bytes + 255) & ~(size_t)255;
        return p;
    };
    int* flags = (int*)alloc(256);
    int* cnt = (int*)alloc((size_t)NN * 4);
    int* indptr = (int*)alloc((size_t)(NN + 1) * 4);
    int* cursor = (int*)alloc((size_t)NN * 4);
    float* recip = (float*)alloc((size_t)NN * 4);
    int* csr = (int*)alloc((size_t)NE * 4);
    const int KDIM[5] = {196, 64, 128, 256, 256};   // source K
    const int KPAD[5] = {256, 64, 128, 256, 256};   // padded K (row stride)
    const int NDIM[5] = {64, 128, 256, 256, 576};
    bf16 *Wlb[5], *Wrb[5];
    float *bf_[5], *gf[4], *bef[4];
    for (int i = 0; i < 5; ++i) {
        Wlb[i] = (bf16*)alloc((size_t)KPAD[i] * NDIM[i] * 2);
        Wrb[i] = (bf16*)alloc((size_t)KPAD[i] * NDIM[i] * 2);
        bf_[i] = (float*)alloc((size_t)NDIM[i] * 4);
    }
    for (int i = 0; i < 4; ++i) {
        gf[i] = (float*)alloc((size_t)NDIM[i] * 4);
        bef[i] = (float*)alloc((size_t)NDIM[i] * 4);
    }
    float* stats = (float*)alloc(1408 * 4);
    float* scale = (float*)alloc(256 * 4);
    float* shift = (float*)alloc(256 * 4);
    float *s1 = stats, *s2 = stats + 128, *s3 = stats + 384, *s4 = stats + 896;
    // big slots
    bf16* aggb = (bf16*)alloc((size_t)NN * 256 * 2);  // also holds xb (NN x 256 padded)
    bf16* S1 = (bf16*)alloc((size_t)NN * 256 * 2);
    bf16* S2 = (bf16*)alloc((size_t)NN * 256 * 2);
    bf16* xb = aggb;
    bf16* u1 = S2;

    if (off > ws_size) {
        long long n = (long long)NN * 576;
        fill_kernel<<<(int)((n + 255) / 256), 256, 0, stream>>>((bf16*)d_out, n);
        return;
    }

    hipMemsetAsync(cnt, 0, (size_t)NN * 4, stream);
    hipMemsetAsync(stats, 0, 1408 * 4, stream);

    detect_kernel<<<1, 64, 0, stream>>>((const unsigned int*)x_raw, flags);

    // canonicalize inputs to bf16 (K-padded) / fp32
    {
        int totx = NN * (KPAD[0] >> 2);
        cvt_pad_kernel<<<(totx + 255) / 256, 256, 0, stream>>>(x_raw, xb, NN, 196, 256, flags);
        for (int i = 0; i < 5; ++i) {
            if (KPAD[i] != KDIM[i]) {
                int tot = NDIM[i] * (KPAD[i] >> 2);
                cvt_pad_kernel<<<(tot + 255) / 256, 256, 0, stream>>>(
                    d_in[2 + 3 * i], Wlb[i], NDIM[i], KDIM[i], KPAD[i], flags);
                cvt_pad_kernel<<<(tot + 255) / 256, 256, 0, stream>>>(
                    d_in[3 + 3 * i], Wrb[i], NDIM[i], KDIM[i], KPAD[i], flags);
            } else {
                int nw4 = KDIM[i] * NDIM[i] / 4;
                cvt_bf16_kernel<<<(nw4 + 255) / 256, 256, 0, stream>>>(d_in[2 + 3 * i], Wlb[i], nw4, flags);
                cvt_bf16_kernel<<<(nw4 + 255) / 256, 256, 0, stream>>>(d_in[3 + 3 * i], Wrb[i], nw4, flags);
            }
            cvt_f32_kernel<<<(NDIM[i] + 255) / 256, 256, 0, stream>>>(d_in[4 + 3 * i], bf_[i], NDIM[i], flags);
        }
        for (int i = 0; i < 4; ++i) {
            cvt_f32_kernel<<<(NDIM[i] + 255) / 256, 256, 0, stream>>>(d_in[17 + 2 * i], gf[i], NDIM[i], flags);
            cvt_f32_kernel<<<(NDIM[i] + 255) / 256, 256, 0, stream>>>(d_in[18 + 2 * i], bef[i], NDIM[i], flags);
        }
    }

    count_kernel<<<(NE + 255) / 256, 256, 0, stream>>>(dst, cnt);
    scan_kernel<<<1, 1024, 0, stream>>>(cnt, indptr, cursor, recip);
    scatter_kernel<<<(NE + 255) / 256, 256, 0, stream>>>(src, dst, cursor, csr);

    const int GM = (NN + 63) / 64;     // bn_stats grid (layer 1 only)
    const int GY = (NN + 255) / 256;   // gemm M-tiles (391)

    // ---- Layer 1: 196(pad 256) -> 64 (aggregate AFTER lin_l)
    gemm_kernel<<<dim3(1, GY), 256, 0, stream>>>(xb, Wlb[0], 256, nullptr, nullptr, 0,
                                                 nullptr, u1, nullptr, nullptr, flags, NN, 64);
    gemm_kernel<<<dim3(1, GY), 256, 0, stream>>>(xb, Wrb[0], 256, nullptr, nullptr, 0,
                                                 bf_[0], S1, nullptr, nullptr, flags, NN, 64);
    aggv_kernel<64, 1><<<NN / 32, 256, 0, stream>>>(u1, indptr, csr, recip, S1);
    bn_stats_kernel<<<GM, 256, 0, stream>>>(S1, 6, s1);
    bn_finalize_kernel<<<1, 256, 0, stream>>>(s1, gf[0], bef[0], 64, scale, shift);
    bn_apply_kernel<<<(NN * 64 / 8 + 255) / 256, 256, 0, stream>>>(S1, scale, shift, 63, S1,
                                                                   (long long)NN * 64 / 8);

    // ---- Layer 2: 64 -> 128  (act1 in S1)
    aggv_kernel<64, 0><<<NN / 32, 256, 0, stream>>>(S1, indptr, csr, recip, aggb);
    gemm_kernel<<<dim3(2, GY), 256, 0, stream>>>(aggb, Wlb[1], 64, S1, Wrb[1], 64,
                                                 bf_[1], S2, nullptr, s2, flags, NN, 128);
    bn_finalize_kernel<<<1, 256, 0, stream>>>(s2, gf[1], bef[1], 128, scale, shift);
    bn_apply_kernel<<<(NN * 128 / 8 + 255) / 256, 256, 0, stream>>>(S2, scale, shift, 127, S2,
                                                                    (long long)NN * 128 / 8);

    // ---- Layer 3: 128 -> 256  (act2 in S2)
    aggv_kernel<128, 0><<<NN / 16, 256, 0, stream>>>(S2, indptr, csr, recip, aggb);
    gemm_kernel<<<dim3(4, GY), 256, 0, stream>>>(aggb, Wlb[2], 128, S2, Wrb[2], 128,
                                                 bf_[2], S1, nullptr, s3, flags, NN, 256);
    bn_finalize_kernel<<<1, 256, 0, stream>>>(s3, gf[2], bef[2], 256, scale, shift);
    bn_apply_kernel<<<(NN * 256 / 8 + 255) / 256, 256, 0, stream>>>(S1, scale, shift, 255, S1,
                                                                    (long long)NN * 256 / 8);

    // ---- Layer 4: 256 -> 256  (act3 in S1)
    aggv_kernel<256, 0><<<NN / 8, 256, 0, stream>>>(S1, indptr, csr, recip, aggb);
    gemm_kernel<<<dim3(4, GY), 256, 0, stream>>>(aggb, Wlb[3], 256, S1, Wrb[3], 256,
                                                 bf_[3], S2, nullptr, s4, flags, NN, 256);
    bn_finalize_kernel<<<1, 256, 0, stream>>>(s4, gf[3], bef[3], 256, scale, shift);
    bn_apply_kernel<<<(NN * 256 / 8 + 255) / 256, 256, 0, stream>>>(S2, scale, shift, 255, S2,
                                                                    (long long)NN * 256 / 8);

    // ---- Layer 5: 256 -> 576, no BN/ReLU, write d_out (bf16 or fp32 per flag)
    aggv_kernel<256, 0><<<NN / 8, 256, 0, stream>>>(S2, indptr, csr, recip, aggb);
    gemm_kernel<<<dim3(9, GY), 256, 0, stream>>>(aggb, Wlb[4], 256, S2, Wrb[4], 256,
                                                 bf_[4], nullptr, d_out, nullptr, flags, NN, 576);
}

// Round 3
// 1464.313 us; speedup vs baseline: 2.8218x; 1.2046x over previous
//
#include <hip/hip_runtime.h>
#include <hip/hip_bf16.h>

typedef __hip_bfloat16 bf16;
typedef __attribute__((ext_vector_type(8))) short short8;
typedef __attribute__((ext_vector_type(4))) float f32x4;

#define NN 100000
#define NE 1600000

__device__ __forceinline__ float bf2f(short s) {
    return __uint_as_float(((unsigned int)(unsigned short)s) << 16);
}
__device__ __forceinline__ short f2bf(float f) {
    union { bf16 b; short s; } u;
    u.b = __float2bfloat16(f);
    return u.s;
}

// ---------------- dtype detection ----------------
__global__ void detect_kernel(const unsigned int* __restrict__ x, int* __restrict__ flags) {
    __shared__ int s;
    if (threadIdx.x == 0) s = 0;
    __syncthreads();
    int c = 0;
    for (int j = 0; j < 4; ++j) {
        unsigned int w = x[threadIdx.x * 4 + j];
        unsigned int e = (w >> 7) & 0xFF;
        if (e >= 100 && e <= 141) c++;
    }
    atomicAdd(&s, c);
    __syncthreads();
    if (threadIdx.x == 0) flags[0] = (s > 128) ? 1 : 0;
}

// ---------------- input canonicalization ----------------
__global__ __launch_bounds__(256) void cvt_bf16_kernel(const void* __restrict__ in,
                                                       bf16* __restrict__ out, int n4,
                                                       const int* __restrict__ flagp) {
    int i = blockIdx.x * 256 + threadIdx.x;
    if (i >= n4) return;
    if (flagp[0]) {
        ((uint2*)out)[i] = ((const uint2*)in)[i];
    } else {
        float4 f = ((const float4*)in)[i];
        size_t o = (size_t)i * 4;
        out[o + 0] = __float2bfloat16(f.x);
        out[o + 1] = __float2bfloat16(f.y);
        out[o + 2] = __float2bfloat16(f.z);
        out[o + 3] = __float2bfloat16(f.w);
    }
}

// rows x sk (src) -> rows x dk (dst, zero-padded cols sk..dk). sk%4==0, dk%4==0.
__global__ __launch_bounds__(256) void cvt_pad_kernel(const void* __restrict__ in,
                                                      bf16* __restrict__ out,
                                                      int rows, int sk, int dk,
                                                      const int* __restrict__ flagp) {
    int i = blockIdx.x * 256 + threadIdx.x;
    int g4 = dk >> 2;
    if (i >= rows * g4) return;
    int row = i / g4;
    int c = (i - row * g4) * 4;
    uint2 w;
    w.x = 0u; w.y = 0u;
    if (c < sk) {
        if (flagp[0]) {
            w = *(const uint2*)((const char*)in + ((size_t)row * sk + c) * 2);
        } else {
            const float* f = (const float*)((const char*)in + ((size_t)row * sk + c) * 4);
            union { bf16 t[4]; uint2 u; } pk;
            pk.t[0] = __float2bfloat16(f[0]);
            pk.t[1] = __float2bfloat16(f[1]);
            pk.t[2] = __float2bfloat16(f[2]);
            pk.t[3] = __float2bfloat16(f[3]);
            w = pk.u;
        }
    }
    *(uint2*)((char*)out + ((size_t)row * dk + c) * 2) = w;
}

__global__ __launch_bounds__(256) void cvt_f32_kernel(const void* __restrict__ in,
                                                      float* __restrict__ out, int n,
                                                      const int* __restrict__ flagp) {
    int i = blockIdx.x * 256 + threadIdx.x;
    if (i >= n) return;
    if (flagp[0]) out[i] = __bfloat162float(((const bf16*)in)[i]);
    else out[i] = ((const float*)in)[i];
}

__global__ __launch_bounds__(256) void fill_kernel(bf16* __restrict__ out, long long n) {
    long long i = (long long)blockIdx.x * 256 + threadIdx.x;
    if (i < n) out[i] = __float2bfloat16(1000.0f);
}

// ---------------- CSR build ----------------

__global__ __launch_bounds__(256) void count_kernel(const int* __restrict__ dst,
                                                    int* __restrict__ cnt) {
    int e = blockIdx.x * 256 + threadIdx.x;
    if (e < NE) atomicAdd(&cnt[dst[e]], 1);
}

// 3-phase device-wide exclusive scan over cnt[NN] (1024 elems per block).
#define SCAN_NB ((NN + 1023) / 1024)  // 98

__global__ __launch_bounds__(256) void scan_partial_kernel(const int* __restrict__ cnt,
                                                           int* __restrict__ bsum) {
    __shared__ int lds[256];
    int t = threadIdx.x;
    int base = blockIdx.x * 1024 + t * 4;
    int s = 0;
#pragma unroll
    for (int i = 0; i < 4; ++i) {
        int idx = base + i;
        if (idx < NN) s += cnt[idx];
    }
    lds[t] = s;
    __syncthreads();
    for (int h = 128; h > 0; h >>= 1) {
        if (t < h) lds[t] += lds[t + h];
        __syncthreads();
    }
    if (t == 0) bsum[blockIdx.x] = lds[0];
}

__global__ __launch_bounds__(128) void scan_bsum_kernel(int* __restrict__ bsum,
                                                        int* __restrict__ indptr) {
    __shared__ int lds[128];
    int t = threadIdx.x;
    int v = (t < SCAN_NB) ? bsum[t] : 0;
    lds[t] = v;
    __syncthreads();
    for (int off = 1; off < 128; off <<= 1) {
        int x = (t >= off) ? lds[t - off] : 0;
        __syncthreads();
        lds[t] += x;
        __syncthreads();
    }
    if (t < SCAN_NB) bsum[t] = lds[t] - v;  // exclusive
    if (t == 127) indptr[NN] = lds[127];
}

__global__ __launch_bounds__(256) void scan_apply_kernel(const int* __restrict__ cnt,
                                                         const int* __restrict__ bsum,
                                                         int* __restrict__ indptr,
                                                         int* __restrict__ cursor,
                                                         float* __restrict__ recip) {
    __shared__ int lds[256];
    int t = threadIdx.x;
    int base = blockIdx.x * 1024 + t * 4;
    int c[4];
    int s = 0;
#pragma unroll
    for (int i = 0; i < 4; ++i) {
        int idx = base + i;
        c[i] = (idx < NN) ? cnt[idx] : 0;
        s += c[i];
    }
    lds[t] = s;
    __syncthreads();
    for (int off = 1; off < 256; off <<= 1) {
        int x = (t >= off) ? lds[t - off] : 0;
        __syncthreads();
        lds[t] += x;
        __syncthreads();
    }
    int run = bsum[blockIdx.x] + lds[t] - s;  // exclusive prefix
#pragma unroll
    for (int i = 0; i < 4; ++i) {
        int idx = base + i;
        if (idx < NN) {
            indptr[idx] = run;
            cursor[idx] = run;
            recip[idx] = 1.0f / (float)(c[i] > 1 ? c[i] : 1);
            run += c[i];
        }
    }
}

__global__ __launch_bounds__(256) void scatter_kernel(const int* __restrict__ src,
                                                      const int* __restrict__ dst,
                                                      int* __restrict__ cursor,
                                                      int* __restrict__ csr) {
    int e = blockIdx.x * 256 + threadIdx.x;
    if (e < NE) {
        int d = dst[e];
        int p = atomicAdd(&cursor[d], 1);
        csr[p] = src[e];
    }
}

// ---------------- aggregation (pull over CSR), vectorized 16B/lane ----------------
template <int D, int ADD>
__global__ __launch_bounds__(256) void aggv_kernel(const bf16* __restrict__ u,
                                                   const int* __restrict__ indptr,
                                                   const int* __restrict__ csr,
                                                   const float* __restrict__ recip,
                                                   bf16* __restrict__ out) {
    constexpr int TPR = D / 8;       // threads per node row
    constexpr int NPB = 256 / TPR;   // nodes per block
    const int tid = threadIdx.x;
    const int node = blockIdx.x * NPB + tid / TPR;
    if (node >= NN) return;
    const int c0 = (tid % TPR) * 8;
    const short* ub = (const short*)u + c0;
    const int j0 = indptr[node], j1 = indptr[node + 1];
    float acc[8];
#pragma unroll
    for (int t = 0; t < 8; ++t) acc[t] = 0.f;
    int j = j0;
    for (; j + 3 < j1; j += 4) {
        int s0 = csr[j], s1 = csr[j + 1], s2 = csr[j + 2], s3 = csr[j + 3];
        short8 v0 = *(const short8*)(ub + (size_t)s0 * D);
        short8 v1 = *(const short8*)(ub + (size_t)s1 * D);
        short8 v2 = *(const short8*)(ub + (size_t)s2 * D);
        short8 v3 = *(const short8*)(ub + (size_t)s3 * D);
#pragma unroll
        for (int t = 0; t < 8; ++t)
            acc[t] += (bf2f(v0[t]) + bf2f(v1[t])) + (bf2f(v2[t]) + bf2f(v3[t]));
    }
    for (; j < j1; ++j) {
        short8 v0 = *(const short8*)(ub + (size_t)csr[j] * D);
#pragma unroll
        for (int t = 0; t < 8; ++t) acc[t] += bf2f(v0[t]);
    }
    const float r = recip[node];
    size_t o = (size_t)node * D + c0;
    short8 w;
    if (ADD) {
        short8 prev = *(const short8*)((const short*)out + o);
#pragma unroll
        for (int t = 0; t < 8; ++t) w[t] = f2bf(acc[t] * r + bf2f(prev[t]));
    } else {
#pragma unroll
        for (int t = 0; t < 8; ++t) w[t] = f2bf(acc[t] * r);
    }
    *(short8*)((short*)out + o) = w;
}

// ---------------- bf16 MFMA GEMM:  out = A1@W1^T (+ A2@W2^T) (+ bias) ----------------
__device__ __forceinline__ void gld_lds16(const void* g, void* l) {
    __builtin_amdgcn_global_load_lds(
        (const __attribute__((address_space(1))) unsigned int*)g,
        (__attribute__((address_space(3))) unsigned int*)l, 16, 0, 0);
}

__global__ __launch_bounds__(256) void gemm_kernel(
    const bf16* __restrict__ A1, const bf16* __restrict__ W1, int K1,
    const bf16* __restrict__ A2, const bf16* __restrict__ W2, int K2,
    const float* __restrict__ bias,
    bf16* __restrict__ outB, void* __restrict__ outFinal,
    float* __restrict__ statp,
    const int* __restrict__ flagp,
    int M, int N) {
    __shared__ alignas(16) char sA[256 * 128];  // 256 rows x 64 bf16 (swizzled)
    __shared__ alignas(16) char sW[64 * 128];   // 64 rows x 64 bf16 (swizzled)

    const int tid = threadIdx.x;
    const int lane = tid & 63, wv = tid >> 6;
    const int lrow = lane & 15, lq = lane >> 4;
    const int n0 = blockIdx.x * 64;
    const int m0 = blockIdx.y * 256;
    const int isbf = flagp[0];

    f32x4 acc[4][4];
#pragma unroll
    for (int a = 0; a < 4; ++a)
#pragma unroll
        for (int b = 0; b < 4; ++b) acc[a][b] = (f32x4){0.f, 0.f, 0.f, 0.f};

    const int sr = tid >> 3;
    const int scb = (tid & 7) << 4;

#pragma unroll 1
    for (int seg = 0; seg < 2; ++seg) {
        const bf16* Ap = seg ? A2 : A1;
        const bf16* Wp = seg ? W2 : W1;
        const int K = seg ? K2 : K1;
        if (K == 0) continue;
#pragma unroll 1
        for (int k0 = 0; k0 < K; k0 += 64) {
            __syncthreads();
#pragma unroll
            for (int i = 0; i < 8; ++i) {
                int row = i * 32 + sr;
                int gr = m0 + row;
                if (gr >= M) gr = M - 1;  // clamp tail (epilogue guards writes)
                const char* g = (const char*)Ap + ((size_t)gr * K + k0) * 2 +
                                (scb ^ ((row & 7) << 4));
                gld_lds16(g, sA + row * 128 + scb);
            }
#pragma unroll
            for (int i = 0; i < 2; ++i) {
                int row = i * 32 + sr;
                const char* g = (const char*)Wp + ((size_t)(n0 + row) * K + k0) * 2 +
                                (scb ^ ((row & 7) << 4));
                gld_lds16(g, sW + row * 128 + scb);
            }
            __syncthreads();
#pragma unroll
            for (int kh = 0; kh < 2; ++kh) {
                short8 a[4], b[4];
                const int cb = kh * 64 + lq * 16;
#pragma unroll
                for (int mi = 0; mi < 4; ++mi) {
                    int row = wv * 64 + mi * 16 + lrow;
                    a[mi] = *(const short8*)(sA + row * 128 + (cb ^ ((row & 7) << 4)));
                }
#pragma unroll
                for (int ni = 0; ni < 4; ++ni) {
                    int row = ni * 16 + lrow;
                    b[ni] = *(const short8*)(sW + row * 128 + (cb ^ ((row & 7) << 4)));
                }
#pragma unroll
                for (int mi = 0; mi < 4; ++mi)
#pragma unroll
                    for (int ni = 0; ni < 4; ++ni)
                        acc[mi][ni] = __builtin_amdgcn_mfma_f32_16x16x32_bf16(
                            a[mi], b[ni], acc[mi][ni], 0, 0, 0);
            }
        }
    }

    // epilogue: C/D layout col=lane&15, row=lq*4+reg; fused BN column stats
#pragma unroll
    for (int ni = 0; ni < 4; ++ni) {
        int gcol = n0 + ni * 16 + lrow;
        float bv = bias ? bias[gcol] : 0.f;
        float s = 0.f, q = 0.f;
#pragma unroll
        for (int mi = 0; mi < 4; ++mi) {
#pragma unroll
            for (int r = 0; r < 4; ++r) {
                int grow = m0 + wv * 64 + mi * 16 + lq * 4 + r;
                if (grow < M) {
                    size_t o = (size_t)grow * N + gcol;
                    float v = acc[mi][ni][r] + bv;
                    s += v;
                    q += v * v;
                    if (outFinal) {
                        if (isbf) ((bf16*)outFinal)[o] = __float2bfloat16(v);
                        else ((float*)outFinal)[o] = v;
                    } else {
                        outB[o] = __float2bfloat16(v);
                    }
                }
            }
        }
        if (statp) {
            s += __shfl_xor(s, 16, 64);
            s += __shfl_xor(s, 32, 64);
            q += __shfl_xor(q, 16, 64);
            q += __shfl_xor(q, 32, 64);
            if (lq == 0) {
                atomicAdd(&statp[gcol], s);
                atomicAdd(&statp[N + gcol], q);
            }
        }
    }
}

// ---------------- BatchNorm ----------------

__global__ __launch_bounds__(256) void bn_stats_kernel(const bf16* __restrict__ C,
                                                       int ldN,
                                                       float* __restrict__ stats) {
    int N = 1 << ldN;
    int tid = threadIdx.x;
    int c = tid & (N - 1);
    int rsub = tid >> ldN;
    int rstep = 256 >> ldN;
    int r0 = blockIdx.x * 64;
    float s = 0.f, q = 0.f;
    for (int r = r0 + rsub; r < r0 + 64; r += rstep) {
        if (r < NN) {
            float v = __bfloat162float(C[(size_t)r * N + c]);
            s += v;
            q += v * v;
        }
    }
    __shared__ float ls[256], lq[256];
    ls[tid] = s;
    lq[tid] = q;
    __syncthreads();
    for (int half = rstep >> 1; half > 0; half >>= 1) {
        if (rsub < half) {
            ls[tid] += ls[tid + half * N];
            lq[tid] += lq[tid + half * N];
        }
        __syncthreads();
    }
    if (rsub == 0) {
        atomicAdd(&stats[c], ls[tid]);
        atomicAdd(&stats[N + c], lq[tid]);
    }
}

__global__ __launch_bounds__(256) void bn_finalize_kernel(const float* __restrict__ stats,
                                                          const float* __restrict__ g,
                                                          const float* __restrict__ be,
                                                          int N,
                                                          float* __restrict__ scale,
                                                          float* __restrict__ shift) {
    int c = threadIdx.x;
    if (c >= N) return;
    float mean = stats[c] * (1.0f / NN);
    float var = stats[N + c] * (1.0f / NN) - mean * mean;
    var = fmaxf(var, 0.f);
    float sc = g[c] * rsqrtf(var + 1e-5f);
    scale[c] = sc;
    shift[c] = be[c] - mean * sc;
}

// in-place ok; 8 bf16 (16B) per thread
__global__ __launch_bounds__(256) void bn_apply_kernel(const bf16* __restrict__ C,
                                                       const float* __restrict__ scale,
                                                       const float* __restrict__ shift,
                                                       int mask,  // N-1 (N>=64)
                                                       bf16* __restrict__ act,
                                                       long long total8) {
    long long i = (long long)blockIdx.x * 256 + threadIdx.x;
    if (i >= total8) return;
    int c0 = (int)((i * 8) & mask);
    short8 v = ((const short8*)C)[i];
    float4 sc0 = *(const float4*)&scale[c0];
    float4 sc1 = *(const float4*)&scale[c0 + 4];
    float4 sh0 = *(const float4*)&shift[c0];
    float4 sh1 = *(const float4*)&shift[c0 + 4];
    short8 w;
#pragma unroll
    for (int t = 0; t < 4; ++t) {
        float x = bf2f(v[t]) * ((const float*)&sc0)[t] + ((const float*)&sh0)[t];
        w[t] = f2bf(x > 0.f ? x : 0.f);
    }
#pragma unroll
    for (int t = 0; t < 4; ++t) {
        float x = bf2f(v[t + 4]) * ((const float*)&sc1)[t] + ((const float*)&sh1)[t];
        w[t + 4] = f2bf(x > 0.f ? x : 0.f);
    }
    ((short8*)act)[i] = w;
}

// ---------------- host launch ----------------

extern "C" void kernel_launch(void* const* d_in, const int* in_sizes, int n_in,
                              void* d_out, int out_size, void* d_ws, size_t ws_size,
                              hipStream_t stream) {
    const void* x_raw = d_in[0];
    const int* ei = (const int*)d_in[1];
    const int* src = ei;
    const int* dst = ei + NE;

    char* w = (char*)d_ws;
    size_t off = 0;
    auto alloc = [&](size_t bytes) {
        void* p = w + off;
        off = (off + bytes + 255) & ~(size_t)255;
        return p;
    };
    int* flags = (int*)alloc(256);
    int* cnt = (int*)alloc((size_t)NN * 4);
    int* indptr = (int*)alloc((size_t)(NN + 1) * 4);
    int* cursor = (int*)alloc((size_t)NN * 4);
    float* recip = (float*)alloc((size_t)NN * 4);
    int* csr = (int*)alloc((size_t)NE * 4);
    int* bsum = (int*)alloc((size_t)SCAN_NB * 4);
    const int KDIM[5] = {196, 64, 128, 256, 256};   // source K
    const int KPAD[5] = {256, 64, 128, 256, 256};   // padded K (row stride)
    const int NDIM[5] = {64, 128, 256, 256, 576};
    bf16 *Wlb[5], *Wrb[5];
    float *bf_[5], *gf[4], *bef[4];
    for (int i = 0; i < 5; ++i) {
        Wlb[i] = (bf16*)alloc((size_t)KPAD[i] * NDIM[i] * 2);
        Wrb[i] = (bf16*)alloc((size_t)KPAD[i] * NDIM[i] * 2);
        bf_[i] = (float*)alloc((size_t)NDIM[i] * 4);
    }
    for (int i = 0; i < 4; ++i) {
        gf[i] = (float*)alloc((size_t)NDIM[i] * 4);
        bef[i] = (float*)alloc((size_t)NDIM[i] * 4);
    }
    float* stats = (float*)alloc(1408 * 4);
    float* scale = (float*)alloc(256 * 4);
    float* shift = (float*)alloc(256 * 4);
    float *s1 = stats, *s2 = stats + 128, *s3 = stats + 384, *s4 = stats + 896;
    // big slots
    bf16* aggb = (bf16*)alloc((size_t)NN * 256 * 2);  // also holds xb (NN x 256 padded)
    bf16* S1 = (bf16*)alloc((size_t)NN * 256 * 2);
    bf16* S2 = (bf16*)alloc((size_t)NN * 256 * 2);
    bf16* xb = aggb;
    bf16* u1 = S2;

    if (off > ws_size) {
        long long n = (long long)NN * 576;
        fill_kernel<<<(int)((n + 255) / 256), 256, 0, stream>>>((bf16*)d_out, n);
        return;
    }

    hipMemsetAsync(cnt, 0, (size_t)NN * 4, stream);
    hipMemsetAsync(stats, 0, 1408 * 4, stream);

    detect_kernel<<<1, 64, 0, stream>>>((const unsigned int*)x_raw, flags);

    // canonicalize inputs to bf16 (K-padded) / fp32
    {
        int totx = NN * (KPAD[0] >> 2);
        cvt_pad_kernel<<<(totx + 255) / 256, 256, 0, stream>>>(x_raw, xb, NN, 196, 256, flags);
        for (int i = 0; i < 5; ++i) {
            if (KPAD[i] != KDIM[i]) {
                int tot = NDIM[i] * (KPAD[i] >> 2);
                cvt_pad_kernel<<<(tot + 255) / 256, 256, 0, stream>>>(
                    d_in[2 + 3 * i], Wlb[i], NDIM[i], KDIM[i], KPAD[i], flags);
                cvt_pad_kernel<<<(tot + 255) / 256, 256, 0, stream>>>(
                    d_in[3 + 3 * i], Wrb[i], NDIM[i], KDIM[i], KPAD[i], flags);
            } else {
                int nw4 = KDIM[i] * NDIM[i] / 4;
                cvt_bf16_kernel<<<(nw4 + 255) / 256, 256, 0, stream>>>(d_in[2 + 3 * i], Wlb[i], nw4, flags);
                cvt_bf16_kernel<<<(nw4 + 255) / 256, 256, 0, stream>>>(d_in[3 + 3 * i], Wrb[i], nw4, flags);
            }
            cvt_f32_kernel<<<(NDIM[i] + 255) / 256, 256, 0, stream>>>(d_in[4 + 3 * i], bf_[i], NDIM[i], flags);
        }
        for (int i = 0; i < 4; ++i) {
            cvt_f32_kernel<<<(NDIM[i] + 255) / 256, 256, 0, stream>>>(d_in[17 + 2 * i], gf[i], NDIM[i], flags);
            cvt_f32_kernel<<<(NDIM[i] + 255) / 256, 256, 0, stream>>>(d_in[18 + 2 * i], bef[i], NDIM[i], flags);
        }
    }

    count_kernel<<<(NE + 255) / 256, 256, 0, stream>>>(dst, cnt);
    scan_partial_kernel<<<SCAN_NB, 256, 0, stream>>>(cnt, bsum);
    scan_bsum_kernel<<<1, 128, 0, stream>>>(bsum, indptr);
    scan_apply_kernel<<<SCAN_NB, 256, 0, stream>>>(cnt, bsum, indptr, cursor, recip);
    scatter_kernel<<<(NE + 255) / 256, 256, 0, stream>>>(src, dst, cursor, csr);

    const int GM = (NN + 63) / 64;     // bn_stats grid (layer 1 only)
    const int GY = (NN + 255) / 256;   // gemm M-tiles (391)

    // ---- Layer 1: 196(pad 256) -> 64 (aggregate AFTER lin_l)
    gemm_kernel<<<dim3(1, GY), 256, 0, stream>>>(xb, Wlb[0], 256, nullptr, nullptr, 0,
                                                 nullptr, u1, nullptr, nullptr, flags, NN, 64);
    gemm_kernel<<<dim3(1, GY), 256, 0, stream>>>(xb, Wrb[0], 256, nullptr, nullptr, 0,
                                                 bf_[0], S1, nullptr, nullptr, flags, NN, 64);
    aggv_kernel<64, 1><<<NN / 32, 256, 0, stream>>>(u1, indptr, csr, recip, S1);
    bn_stats_kernel<<<GM, 256, 0, stream>>>(S1, 6, s1);
    bn_finalize_kernel<<<1, 256, 0, stream>>>(s1, gf[0], bef[0], 64, scale, shift);
    bn_apply_kernel<<<(NN * 64 / 8 + 255) / 256, 256, 0, stream>>>(S1, scale, shift, 63, S1,
                                                                   (long long)NN * 64 / 8);

    // ---- Layer 2: 64 -> 128  (act1 in S1)
    aggv_kernel<64, 0><<<NN / 32, 256, 0, stream>>>(S1, indptr, csr, recip, aggb);
    gemm_kernel<<<dim3(2, GY), 256, 0, stream>>>(aggb, Wlb[1], 64, S1, Wrb[1], 64,
                                                 bf_[1], S2, nullptr, s2, flags, NN, 128);
    bn_finalize_kernel<<<1, 256, 0, stream>>>(s2, gf[1], bef[1], 128, scale, shift);
    bn_apply_kernel<<<(NN * 128 / 8 + 255) / 256, 256, 0, stream>>>(S2, scale, shift, 127, S2,
                                                                    (long long)NN * 128 / 8);

    // ---- Layer 3: 128 -> 256  (act2 in S2)
    aggv_kernel<128, 0><<<NN / 16, 256, 0, stream>>>(S2, indptr, csr, recip, aggb);
    gemm_kernel<<<dim3(4, GY), 256, 0, stream>>>(aggb, Wlb[2], 128, S2, Wrb[2], 128,
                                                 bf_[2], S1, nullptr, s3, flags, NN, 256);
    bn_finalize_kernel<<<1, 256, 0, stream>>>(s3, gf[2], bef[2], 256, scale, shift);
    bn_apply_kernel<<<(NN * 256 / 8 + 255) / 256, 256, 0, stream>>>(S1, scale, shift, 255, S1,
                                                                    (long long)NN * 256 / 8);

    // ---- Layer 4: 256 -> 256  (act3 in S1)
    aggv_kernel<256, 0><<<NN / 8, 256, 0, stream>>>(S1, indptr, csr, recip, aggb);
    gemm_kernel<<<dim3(4, GY), 256, 0, stream>>>(aggb, Wlb[3], 256, S1, Wrb[3], 256,
                                                 bf_[3], S2, nullptr, s4, flags, NN, 256);
    bn_finalize_kernel<<<1, 256, 0, stream>>>(s4, gf[3], bef[3], 256, scale, shift);
    bn_apply_kernel<<<(NN * 256 / 8 + 255) / 256, 256, 0, stream>>>(S2, scale, shift, 255, S2,
                                                                    (long long)NN * 256 / 8);

    // ---- Layer 5: 256 -> 576, no BN/ReLU, write d_out (bf16 or fp32 per flag)
    aggv_kernel<256, 0><<<NN / 8, 256, 0, stream>>>(S2, indptr, csr, recip, aggb);
    gemm_kernel<<<dim3(9, GY), 256, 0, stream>>>(aggb, Wlb[4], 256, S2, Wrb[4], 256,
                                                 bf_[4], nullptr, d_out, nullptr, flags, NN, 576);
}

// Round 4
// 1411.994 us; speedup vs baseline: 2.9264x; 1.0371x over previous
//
#include <hip/hip_runtime.h>
#include <hip/hip_bf16.h>

typedef __hip_bfloat16 bf16;
typedef __attribute__((ext_vector_type(8))) short short8;
typedef __attribute__((ext_vector_type(4))) float f32x4;

#define NN 100000
#define NE 1600000

__device__ __forceinline__ float bf2f(short s) {
    return __uint_as_float(((unsigned int)(unsigned short)s) << 16);
}
__device__ __forceinline__ short f2bf(float f) {
    union { bf16 b; short s; } u;
    u.b = __float2bfloat16(f);
    return u.s;
}

// ---------------- dtype detection ----------------
__global__ void detect_kernel(const unsigned int* __restrict__ x, int* __restrict__ flags) {
    __shared__ int s;
    if (threadIdx.x == 0) s = 0;
    __syncthreads();
    int c = 0;
    for (int j = 0; j < 4; ++j) {
        unsigned int w = x[threadIdx.x * 4 + j];
        unsigned int e = (w >> 7) & 0xFF;
        if (e >= 100 && e <= 141) c++;
    }
    atomicAdd(&s, c);
    __syncthreads();
    if (threadIdx.x == 0) flags[0] = (s > 128) ? 1 : 0;
}

// ---------------- input canonicalization ----------------
__global__ __launch_bounds__(256) void cvt_bf16_kernel(const void* __restrict__ in,
                                                       bf16* __restrict__ out, int n4,
                                                       const int* __restrict__ flagp) {
    int i = blockIdx.x * 256 + threadIdx.x;
    if (i >= n4) return;
    if (flagp[0]) {
        ((uint2*)out)[i] = ((const uint2*)in)[i];
    } else {
        float4 f = ((const float4*)in)[i];
        size_t o = (size_t)i * 4;
        out[o + 0] = __float2bfloat16(f.x);
        out[o + 1] = __float2bfloat16(f.y);
        out[o + 2] = __float2bfloat16(f.z);
        out[o + 3] = __float2bfloat16(f.w);
    }
}

// rows x sk (src) -> rows x dk (dst, zero-padded cols sk..dk). sk%4==0, dk%4==0.
__global__ __launch_bounds__(256) void cvt_pad_kernel(const void* __restrict__ in,
                                                      bf16* __restrict__ out,
                                                      int rows, int sk, int dk,
                                                      const int* __restrict__ flagp) {
    int i = blockIdx.x * 256 + threadIdx.x;
    int g4 = dk >> 2;
    if (i >= rows * g4) return;
    int row = i / g4;
    int c = (i - row * g4) * 4;
    uint2 w;
    w.x = 0u; w.y = 0u;
    if (c < sk) {
        if (flagp[0]) {
            w = *(const uint2*)((const char*)in + ((size_t)row * sk + c) * 2);
        } else {
            const float* f = (const float*)((const char*)in + ((size_t)row * sk + c) * 4);
            union { bf16 t[4]; uint2 u; } pk;
            pk.t[0] = __float2bfloat16(f[0]);
            pk.t[1] = __float2bfloat16(f[1]);
            pk.t[2] = __float2bfloat16(f[2]);
            pk.t[3] = __float2bfloat16(f[3]);
            w = pk.u;
        }
    }
    *(uint2*)((char*)out + ((size_t)row * dk + c) * 2) = w;
}

__global__ __launch_bounds__(256) void cvt_f32_kernel(const void* __restrict__ in,
                                                      float* __restrict__ out, int n,
                                                      const int* __restrict__ flagp) {
    int i = blockIdx.x * 256 + threadIdx.x;
    if (i >= n) return;
    if (flagp[0]) out[i] = __bfloat162float(((const bf16*)in)[i]);
    else out[i] = ((const float*)in)[i];
}

__global__ __launch_bounds__(256) void fill_kernel(bf16* __restrict__ out, long long n) {
    long long i = (long long)blockIdx.x * 256 + threadIdx.x;
    if (i < n) out[i] = __float2bfloat16(1000.0f);
}

// ---------------- CSR build ----------------

__global__ __launch_bounds__(256) void count_kernel(const int* __restrict__ dst,
                                                    int* __restrict__ cnt) {
    int e = blockIdx.x * 256 + threadIdx.x;
    if (e < NE) atomicAdd(&cnt[dst[e]], 1);
}

// 3-phase device-wide exclusive scan over cnt[NN] (1024 elems per block).
#define SCAN_NB ((NN + 1023) / 1024)  // 98

__global__ __launch_bounds__(256) void scan_partial_kernel(const int* __restrict__ cnt,
                                                           int* __restrict__ bsum) {
    __shared__ int lds[256];
    int t = threadIdx.x;
    int base = blockIdx.x * 1024 + t * 4;
    int s = 0;
#pragma unroll
    for (int i = 0; i < 4; ++i) {
        int idx = base + i;
        if (idx < NN) s += cnt[idx];
    }
    lds[t] = s;
    __syncthreads();
    for (int h = 128; h > 0; h >>= 1) {
        if (t < h) lds[t] += lds[t + h];
        __syncthreads();
    }
    if (t == 0) bsum[blockIdx.x] = lds[0];
}

__global__ __launch_bounds__(128) void scan_bsum_kernel(int* __restrict__ bsum,
                                                        int* __restrict__ indptr) {
    __shared__ int lds[128];
    int t = threadIdx.x;
    int v = (t < SCAN_NB) ? bsum[t] : 0;
    lds[t] = v;
    __syncthreads();
    for (int off = 1; off < 128; off <<= 1) {
        int x = (t >= off) ? lds[t - off] : 0;
        __syncthreads();
        lds[t] += x;
        __syncthreads();
    }
    if (t < SCAN_NB) bsum[t] = lds[t] - v;  // exclusive
    if (t == 127) indptr[NN] = lds[127];
}

__global__ __launch_bounds__(256) void scan_apply_kernel(const int* __restrict__ cnt,
                                                         const int* __restrict__ bsum,
                                                         int* __restrict__ indptr,
                                                         int* __restrict__ cursor,
                                                         float* __restrict__ recip) {
    __shared__ int lds[256];
    int t = threadIdx.x;
    int base = blockIdx.x * 1024 + t * 4;
    int c[4];
    int s = 0;
#pragma unroll
    for (int i = 0; i < 4; ++i) {
        int idx = base + i;
        c[i] = (idx < NN) ? cnt[idx] : 0;
        s += c[i];
    }
    lds[t] = s;
    __syncthreads();
    for (int off = 1; off < 256; off <<= 1) {
        int x = (t >= off) ? lds[t - off] : 0;
        __syncthreads();
        lds[t] += x;
        __syncthreads();
    }
    int run = bsum[blockIdx.x] + lds[t] - s;  // exclusive prefix
#pragma unroll
    for (int i = 0; i < 4; ++i) {
        int idx = base + i;
        if (idx < NN) {
            indptr[idx] = run;
            cursor[idx] = run;
            recip[idx] = 1.0f / (float)(c[i] > 1 ? c[i] : 1);
            run += c[i];
        }
    }
}

__global__ __launch_bounds__(256) void scatter_kernel(const int* __restrict__ src,
                                                      const int* __restrict__ dst,
                                                      int* __restrict__ cursor,
                                                      int* __restrict__ csr) {
    int e = blockIdx.x * 256 + threadIdx.x;
    if (e < NE) {
        int d = dst[e];
        int p = atomicAdd(&cursor[d], 1);
        csr[p] = src[e];
    }
}

// ---------------- aggregation (pull over CSR), vectorized 16B/lane ----------------
template <int D, int ADD>
__global__ __launch_bounds__(256) void aggv_kernel(const bf16* __restrict__ u,
                                                   const int* __restrict__ indptr,
                                                   const int* __restrict__ csr,
                                                   const float* __restrict__ recip,
                                                   bf16* __restrict__ out) {
    constexpr int TPR = D / 8;       // threads per node row
    constexpr int NPB = 256 / TPR;   // nodes per block
    const int tid = threadIdx.x;
    const int node = blockIdx.x * NPB + tid / TPR;
    if (node >= NN) return;
    const int c0 = (tid % TPR) * 8;
    const short* ub = (const short*)u + c0;
    const int j0 = indptr[node], j1 = indptr[node + 1];
    float acc[8];
#pragma unroll
    for (int t = 0; t < 8; ++t) acc[t] = 0.f;
    int j = j0;
    for (; j + 3 < j1; j += 4) {
        int s0 = csr[j], s1 = csr[j + 1], s2 = csr[j + 2], s3 = csr[j + 3];
        short8 v0 = *(const short8*)(ub + (size_t)s0 * D);
        short8 v1 = *(const short8*)(ub + (size_t)s1 * D);
        short8 v2 = *(const short8*)(ub + (size_t)s2 * D);
        short8 v3 = *(const short8*)(ub + (size_t)s3 * D);
#pragma unroll
        for (int t = 0; t < 8; ++t)
            acc[t] += (bf2f(v0[t]) + bf2f(v1[t])) + (bf2f(v2[t]) + bf2f(v3[t]));
    }
    for (; j < j1; ++j) {
        short8 v0 = *(const short8*)(ub + (size_t)csr[j] * D);
#pragma unroll
        for (int t = 0; t < 8; ++t) acc[t] += bf2f(v0[t]);
    }
    const float r = recip[node];
    size_t o = (size_t)node * D + c0;
    short8 w;
    if (ADD) {
        short8 prev = *(const short8*)((const short*)out + o);
#pragma unroll
        for (int t = 0; t < 8; ++t) w[t] = f2bf(acc[t] * r + bf2f(prev[t]));
    } else {
#pragma unroll
        for (int t = 0; t < 8; ++t) w[t] = f2bf(acc[t] * r);
    }
    *(short8*)((short*)out + o) = w;
}

// ---------------- bf16 MFMA GEMM:  out = A1@W1^T (+ A2@W2^T) (+ bias) ----------------
__device__ __forceinline__ void gld_lds16(const void* g, void* l) {
    __builtin_amdgcn_global_load_lds(
        (const __attribute__((address_space(1))) unsigned int*)g,
        (__attribute__((address_space(3))) unsigned int*)l, 16, 0, 0);
}

__global__ __launch_bounds__(256) void gemm_kernel(
    const bf16* __restrict__ A1, const bf16* __restrict__ W1, int K1,
    const bf16* __restrict__ A2, const bf16* __restrict__ W2, int K2,
    const float* __restrict__ bias,
    bf16* __restrict__ outB, void* __restrict__ outFinal,
    float* __restrict__ statp,
    const int* __restrict__ flagp,
    int M, int N) {
    __shared__ alignas(16) char sA[256 * 128];  // 256 rows x 64 bf16 (swizzled)
    __shared__ alignas(16) char sW[64 * 128];   // 64 rows x 64 bf16 (swizzled)

    const int tid = threadIdx.x;
    const int lane = tid & 63, wv = tid >> 6;
    const int lrow = lane & 15, lq = lane >> 4;

    // XCD-aware bijective swizzle (T1, m204 formula): consecutive blocks land
    // on XCDs round-robin; remap so each XCD owns contiguous m-tiles with all
    // their n-tiles adjacent -> A-panel fetched once per XCD L2, reused by all
    // n-tiles of the m-tile.
    const int nwg = gridDim.x * gridDim.y;
    const int flat = blockIdx.y * gridDim.x + blockIdx.x;
    const int xcd = flat & 7;
    const int rest = flat >> 3;
    const int q = nwg >> 3, r = nwg & 7;
    const int chunk = (xcd < r) ? xcd * (q + 1) : r * (q + 1) + (xcd - r) * q;
    const int newid = chunk + rest;
    const int n0 = (newid % gridDim.x) * 64;
    const int m0 = (newid / gridDim.x) * 256;

    const int isbf = flagp[0];

    f32x4 acc[4][4];
#pragma unroll
    for (int a = 0; a < 4; ++a)
#pragma unroll
        for (int b = 0; b < 4; ++b) acc[a][b] = (f32x4){0.f, 0.f, 0.f, 0.f};

    const int sr = tid >> 3;
    const int scb = (tid & 7) << 4;

#pragma unroll 1
    for (int seg = 0; seg < 2; ++seg) {
        const bf16* Ap = seg ? A2 : A1;
        const bf16* Wp = seg ? W2 : W1;
        const int K = seg ? K2 : K1;
        if (K == 0) continue;
#pragma unroll 1
        for (int k0 = 0; k0 < K; k0 += 64) {
            __syncthreads();
#pragma unroll
            for (int i = 0; i < 8; ++i) {
                int row = i * 32 + sr;
                int gr = m0 + row;
                if (gr >= M) gr = M - 1;  // clamp tail (epilogue guards writes)
                const char* g = (const char*)Ap + ((size_t)gr * K + k0) * 2 +
                                (scb ^ ((row & 7) << 4));
                gld_lds16(g, sA + row * 128 + scb);
            }
#pragma unroll
            for (int i = 0; i < 2; ++i) {
                int row = i * 32 + sr;
                const char* g = (const char*)Wp + ((size_t)(n0 + row) * K + k0) * 2 +
                                (scb ^ ((row & 7) << 4));
                gld_lds16(g, sW + row * 128 + scb);
            }
            __syncthreads();
#pragma unroll
            for (int kh = 0; kh < 2; ++kh) {
                short8 a[4], b[4];
                const int cb = kh * 64 + lq * 16;
#pragma unroll
                for (int mi = 0; mi < 4; ++mi) {
                    int row = wv * 64 + mi * 16 + lrow;
                    a[mi] = *(const short8*)(sA + row * 128 + (cb ^ ((row & 7) << 4)));
                }
#pragma unroll
                for (int ni = 0; ni < 4; ++ni) {
                    int row = ni * 16 + lrow;
                    b[ni] = *(const short8*)(sW + row * 128 + (cb ^ ((row & 7) << 4)));
                }
#pragma unroll
                for (int mi = 0; mi < 4; ++mi)
#pragma unroll
                    for (int ni = 0; ni < 4; ++ni)
                        acc[mi][ni] = __builtin_amdgcn_mfma_f32_16x16x32_bf16(
                            a[mi], b[ni], acc[mi][ni], 0, 0, 0);
            }
        }
    }

    // epilogue: C/D layout col=lane&15, row=lq*4+reg; fused BN column stats
#pragma unroll
    for (int ni = 0; ni < 4; ++ni) {
        int gcol = n0 + ni * 16 + lrow;
        float bv = bias ? bias[gcol] : 0.f;
        float s = 0.f, q2 = 0.f;
#pragma unroll
        for (int mi = 0; mi < 4; ++mi) {
#pragma unroll
            for (int r2 = 0; r2 < 4; ++r2) {
                int grow = m0 + wv * 64 + mi * 16 + lq * 4 + r2;
                if (grow < M) {
                    size_t o = (size_t)grow * N + gcol;
                    float v = acc[mi][ni][r2] + bv;
                    s += v;
                    q2 += v * v;
                    if (outFinal) {
                        if (isbf) ((bf16*)outFinal)[o] = __float2bfloat16(v);
                        else ((float*)outFinal)[o] = v;
                    } else {
                        outB[o] = __float2bfloat16(v);
                    }
                }
            }
        }
        if (statp) {
            s += __shfl_xor(s, 16, 64);
            s += __shfl_xor(s, 32, 64);
            q2 += __shfl_xor(q2, 16, 64);
            q2 += __shfl_xor(q2, 32, 64);
            if (lq == 0) {
                atomicAdd(&statp[gcol], s);
                atomicAdd(&statp[N + gcol], q2);
            }
        }
    }
}

// ---------------- BatchNorm ----------------

__global__ __launch_bounds__(256) void bn_stats_kernel(const bf16* __restrict__ C,
                                                       int ldN,
                                                       float* __restrict__ stats) {
    int N = 1 << ldN;
    int tid = threadIdx.x;
    int c = tid & (N - 1);
    int rsub = tid >> ldN;
    int rstep = 256 >> ldN;
    int r0 = blockIdx.x * 64;
    float s = 0.f, q = 0.f;
    for (int r = r0 + rsub; r < r0 + 64; r += rstep) {
        if (r < NN) {
            float v = __bfloat162float(C[(size_t)r * N + c]);
            s += v;
            q += v * v;
        }
    }
    __shared__ float ls[256], lq[256];
    ls[tid] = s;
    lq[tid] = q;
    __syncthreads();
    for (int half = rstep >> 1; half > 0; half >>= 1) {
        if (rsub < half) {
            ls[tid] += ls[tid + half * N];
            lq[tid] += lq[tid + half * N];
        }
        __syncthreads();
    }
    if (rsub == 0) {
        atomicAdd(&stats[c], ls[tid]);
        atomicAdd(&stats[N + c], lq[tid]);
    }
}

__global__ __launch_bounds__(256) void bn_finalize_kernel(const float* __restrict__ stats,
                                                          const float* __restrict__ g,
                                                          const float* __restrict__ be,
                                                          int N,
                                                          float* __restrict__ scale,
                                                          float* __restrict__ shift) {
    int c = threadIdx.x;
    if (c >= N) return;
    float mean = stats[c] * (1.0f / NN);
    float var = stats[N + c] * (1.0f / NN) - mean * mean;
    var = fmaxf(var, 0.f);
    float sc = g[c] * rsqrtf(var + 1e-5f);
    scale[c] = sc;
    shift[c] = be[c] - mean * sc;
}

// in-place ok; 8 bf16 (16B) per thread
__global__ __launch_bounds__(256) void bn_apply_kernel(const bf16* __restrict__ C,
                                                       const float* __restrict__ scale,
                                                       const float* __restrict__ shift,
                                                       int mask,  // N-1 (N>=64)
                                                       bf16* __restrict__ act,
                                                       long long total8) {
    long long i = (long long)blockIdx.x * 256 + threadIdx.x;
    if (i >= total8) return;
    int c0 = (int)((i * 8) & mask);
    short8 v = ((const short8*)C)[i];
    float4 sc0 = *(const float4*)&scale[c0];
    float4 sc1 = *(const float4*)&scale[c0 + 4];
    float4 sh0 = *(const float4*)&shift[c0];
    float4 sh1 = *(const float4*)&shift[c0 + 4];
    short8 w;
#pragma unroll
    for (int t = 0; t < 4; ++t) {
        float x = bf2f(v[t]) * ((const float*)&sc0)[t] + ((const float*)&sh0)[t];
        w[t] = f2bf(x > 0.f ? x : 0.f);
    }
#pragma unroll
    for (int t = 0; t < 4; ++t) {
        float x = bf2f(v[t + 4]) * ((const float*)&sc1)[t] + ((const float*)&sh1)[t];
        w[t + 4] = f2bf(x > 0.f ? x : 0.f);
    }
    ((short8*)act)[i] = w;
}

// ---------------- host launch ----------------

extern "C" void kernel_launch(void* const* d_in, const int* in_sizes, int n_in,
                              void* d_out, int out_size, void* d_ws, size_t ws_size,
                              hipStream_t stream) {
    const void* x_raw = d_in[0];
    const int* ei = (const int*)d_in[1];
    const int* src = ei;
    const int* dst = ei + NE;

    char* w = (char*)d_ws;
    size_t off = 0;
    auto alloc = [&](size_t bytes) {
        void* p = w + off;
        off = (off + bytes + 255) & ~(size_t)255;
        return p;
    };
    int* flags = (int*)alloc(256);
    int* cnt = (int*)alloc((size_t)NN * 4);
    int* indptr = (int*)alloc((size_t)(NN + 1) * 4);
    int* cursor = (int*)alloc((size_t)NN * 4);
    float* recip = (float*)alloc((size_t)NN * 4);
    int* csr = (int*)alloc((size_t)NE * 4);
    int* bsum = (int*)alloc((size_t)SCAN_NB * 4);
    const int KDIM[5] = {196, 64, 128, 256, 256};   // source K
    const int KPAD[5] = {256, 64, 128, 256, 256};   // padded K (row stride)
    const int NDIM[5] = {64, 128, 256, 256, 576};
    bf16 *Wlb[5], *Wrb[5];
    float *bf_[5], *gf[4], *bef[4];
    for (int i = 0; i < 5; ++i) {
        Wlb[i] = (bf16*)alloc((size_t)KPAD[i] * NDIM[i] * 2);
        Wrb[i] = (bf16*)alloc((size_t)KPAD[i] * NDIM[i] * 2);
        bf_[i] = (float*)alloc((size_t)NDIM[i] * 4);
    }
    for (int i = 0; i < 4; ++i) {
        gf[i] = (float*)alloc((size_t)NDIM[i] * 4);
        bef[i] = (float*)alloc((size_t)NDIM[i] * 4);
    }
    float* stats = (float*)alloc(1408 * 4);
    float* scale = (float*)alloc(256 * 4);
    float* shift = (float*)alloc(256 * 4);
    float *s1 = stats, *s2 = stats + 128, *s3 = stats + 384, *s4 = stats + 896;
    // big slots
    bf16* aggb = (bf16*)alloc((size_t)NN * 256 * 2);  // also holds xb (NN x 256 padded)
    bf16* S1 = (bf16*)alloc((size_t)NN * 256 * 2);
    bf16* S2 = (bf16*)alloc((size_t)NN * 256 * 2);
    bf16* xb = aggb;
    bf16* u1 = S2;

    if (off > ws_size) {
        long long n = (long long)NN * 576;
        fill_kernel<<<(int)((n + 255) / 256), 256, 0, stream>>>((bf16*)d_out, n);
        return;
    }

    hipMemsetAsync(cnt, 0, (size_t)NN * 4, stream);
    hipMemsetAsync(stats, 0, 1408 * 4, stream);

    detect_kernel<<<1, 64, 0, stream>>>((const unsigned int*)x_raw, flags);

    // canonicalize inputs to bf16 (K-padded) / fp32
    {
        int totx = NN * (KPAD[0] >> 2);
        cvt_pad_kernel<<<(totx + 255) / 256, 256, 0, stream>>>(x_raw, xb, NN, 196, 256, flags);
        for (int i = 0; i < 5; ++i) {
            if (KPAD[i] != KDIM[i]) {
                int tot = NDIM[i] * (KPAD[i] >> 2);
                cvt_pad_kernel<<<(tot + 255) / 256, 256, 0, stream>>>(
                    d_in[2 + 3 * i], Wlb[i], NDIM[i], KDIM[i], KPAD[i], flags);
                cvt_pad_kernel<<<(tot + 255) / 256, 256, 0, stream>>>(
                    d_in[3 + 3 * i], Wrb[i], NDIM[i], KDIM[i], KPAD[i], flags);
            } else {
                int nw4 = KDIM[i] * NDIM[i] / 4;
                cvt_bf16_kernel<<<(nw4 + 255) / 256, 256, 0, stream>>>(d_in[2 + 3 * i], Wlb[i], nw4, flags);
                cvt_bf16_kernel<<<(nw4 + 255) / 256, 256, 0, stream>>>(d_in[3 + 3 * i], Wrb[i], nw4, flags);
            }
            cvt_f32_kernel<<<(NDIM[i] + 255) / 256, 256, 0, stream>>>(d_in[4 + 3 * i], bf_[i], NDIM[i], flags);
        }
        for (int i = 0; i < 4; ++i) {
            cvt_f32_kernel<<<(NDIM[i] + 255) / 256, 256, 0, stream>>>(d_in[17 + 2 * i], gf[i], NDIM[i], flags);
            cvt_f32_kernel<<<(NDIM[i] + 255) / 256, 256, 0, stream>>>(d_in[18 + 2 * i], bef[i], NDIM[i], flags);
        }
    }

    count_kernel<<<(NE + 255) / 256, 256, 0, stream>>>(dst, cnt);
    scan_partial_kernel<<<SCAN_NB, 256, 0, stream>>>(cnt, bsum);
    scan_bsum_kernel<<<1, 128, 0, stream>>>(bsum, indptr);
    scan_apply_kernel<<<SCAN_NB, 256, 0, stream>>>(cnt, bsum, indptr, cursor, recip);
    scatter_kernel<<<(NE + 255) / 256, 256, 0, stream>>>(src, dst, cursor, csr);

    const int GM = (NN + 63) / 64;     // bn_stats grid (layer 1 only)
    const int GY = (NN + 255) / 256;   // gemm M-tiles (391)

    // ---- Layer 1: 196(pad 256) -> 64 (aggregate AFTER lin_l)
    gemm_kernel<<<dim3(1, GY), 256, 0, stream>>>(xb, Wlb[0], 256, nullptr, nullptr, 0,
                                                 nullptr, u1, nullptr, nullptr, flags, NN, 64);
    gemm_kernel<<<dim3(1, GY), 256, 0, stream>>>(xb, Wrb[0], 256, nullptr, nullptr, 0,
                                                 bf_[0], S1, nullptr, nullptr, flags, NN, 64);
    aggv_kernel<64, 1><<<NN / 32, 256, 0, stream>>>(u1, indptr, csr, recip, S1);
    bn_stats_kernel<<<GM, 256, 0, stream>>>(S1, 6, s1);
    bn_finalize_kernel<<<1, 256, 0, stream>>>(s1, gf[0], bef[0], 64, scale, shift);
    bn_apply_kernel<<<(NN * 64 / 8 + 255) / 256, 256, 0, stream>>>(S1, scale, shift, 63, S1,
                                                                   (long long)NN * 64 / 8);

    // ---- Layer 2: 64 -> 128  (act1 in S1)
    aggv_kernel<64, 0><<<NN / 32, 256, 0, stream>>>(S1, indptr, csr, recip, aggb);
    gemm_kernel<<<dim3(2, GY), 256, 0, stream>>>(aggb, Wlb[1], 64, S1, Wrb[1], 64,
                                                 bf_[1], S2, nullptr, s2, flags, NN, 128);
    bn_finalize_kernel<<<1, 256, 0, stream>>>(s2, gf[1], bef[1], 128, scale, shift);
    bn_apply_kernel<<<(NN * 128 / 8 + 255) / 256, 256, 0, stream>>>(S2, scale, shift, 127, S2,
                                                                    (long long)NN * 128 / 8);

    // ---- Layer 3: 128 -> 256  (act2 in S2)
    aggv_kernel<128, 0><<<NN / 16, 256, 0, stream>>>(S2, indptr, csr, recip, aggb);
    gemm_kernel<<<dim3(4, GY), 256, 0, stream>>>(aggb, Wlb[2], 128, S2, Wrb[2], 128,
                                                 bf_[2], S1, nullptr, s3, flags, NN, 256);
    bn_finalize_kernel<<<1, 256, 0, stream>>>(s3, gf[2], bef[2], 256, scale, shift);
    bn_apply_kernel<<<(NN * 256 / 8 + 255) / 256, 256, 0, stream>>>(S1, scale, shift, 255, S1,
                                                                    (long long)NN * 256 / 8);

    // ---- Layer 4: 256 -> 256  (act3 in S1)
    aggv_kernel<256, 0><<<NN / 8, 256, 0, stream>>>(S1, indptr, csr, recip, aggb);
    gemm_kernel<<<dim3(4, GY), 256, 0, stream>>>(aggb, Wlb[3], 256, S1, Wrb[3], 256,
                                                 bf_[3], S2, nullptr, s4, flags, NN, 256);
    bn_finalize_kernel<<<1, 256, 0, stream>>>(s4, gf[3], bef[3], 256, scale, shift);
    bn_apply_kernel<<<(NN * 256 / 8 + 255) / 256, 256, 0, stream>>>(S2, scale, shift, 255, S2,
                                                                    (long long)NN * 256 / 8);

    // ---- Layer 5: 256 -> 576, no BN/ReLU, write d_out (bf16 or fp32 per flag)
    aggv_kernel<256, 0><<<NN / 8, 256, 0, stream>>>(S2, indptr, csr, recip, aggb);
    gemm_kernel<<<dim3(9, GY), 256, 0, stream>>>(aggb, Wlb[4], 256, S2, Wrb[4], 256,
                                                 bf_[4], nullptr, d_out, nullptr, flags, NN, 576);
}

// Round 5
// 1309.433 us; speedup vs baseline: 3.1556x; 1.0783x over previous
//
#include <hip/hip_runtime.h>
#include <hip/hip_bf16.h>

typedef __hip_bfloat16 bf16;
typedef __attribute__((ext_vector_type(8))) short short8;
typedef __attribute__((ext_vector_type(4))) float f32x4;

#define NN 100000
#define NE 1600000

__device__ __forceinline__ float bf2f(short s) {
    return __uint_as_float(((unsigned int)(unsigned short)s) << 16);
}
__device__ __forceinline__ short f2bf(float f) {
    union { bf16 b; short s; } u;
    u.b = __float2bfloat16(f);
    return u.s;
}

// ---------------- dtype detection ----------------
__global__ void detect_kernel(const unsigned int* __restrict__ x, int* __restrict__ flags) {
    __shared__ int s;
    if (threadIdx.x == 0) s = 0;
    __syncthreads();
    int c = 0;
    for (int j = 0; j < 4; ++j) {
        unsigned int w = x[threadIdx.x * 4 + j];
        unsigned int e = (w >> 7) & 0xFF;
        if (e >= 100 && e <= 141) c++;
    }
    atomicAdd(&s, c);
    __syncthreads();
    if (threadIdx.x == 0) flags[0] = (s > 128) ? 1 : 0;
}

// ---------------- input canonicalization ----------------
__global__ __launch_bounds__(256) void cvt_bf16_kernel(const void* __restrict__ in,
                                                       bf16* __restrict__ out, int n4,
                                                       const int* __restrict__ flagp) {
    int i = blockIdx.x * 256 + threadIdx.x;
    if (i >= n4) return;
    if (flagp[0]) {
        ((uint2*)out)[i] = ((const uint2*)in)[i];
    } else {
        float4 f = ((const float4*)in)[i];
        size_t o = (size_t)i * 4;
        out[o + 0] = __float2bfloat16(f.x);
        out[o + 1] = __float2bfloat16(f.y);
        out[o + 2] = __float2bfloat16(f.z);
        out[o + 3] = __float2bfloat16(f.w);
    }
}

// rows x sk (src) -> rows x dk (dst, zero-padded cols sk..dk). sk%4==0, dk%4==0.
__global__ __launch_bounds__(256) void cvt_pad_kernel(const void* __restrict__ in,
                                                      bf16* __restrict__ out,
                                                      int rows, int sk, int dk,
                                                      const int* __restrict__ flagp) {
    int i = blockIdx.x * 256 + threadIdx.x;
    int g4 = dk >> 2;
    if (i >= rows * g4) return;
    int row = i / g4;
    int c = (i - row * g4) * 4;
    uint2 w;
    w.x = 0u; w.y = 0u;
    if (c < sk) {
        if (flagp[0]) {
            w = *(const uint2*)((const char*)in + ((size_t)row * sk + c) * 2);
        } else {
            const float* f = (const float*)((const char*)in + ((size_t)row * sk + c) * 4);
            union { bf16 t[4]; uint2 u; } pk;
            pk.t[0] = __float2bfloat16(f[0]);
            pk.t[1] = __float2bfloat16(f[1]);
            pk.t[2] = __float2bfloat16(f[2]);
            pk.t[3] = __float2bfloat16(f[3]);
            w = pk.u;
        }
    }
    *(uint2*)((char*)out + ((size_t)row * dk + c) * 2) = w;
}

__global__ __launch_bounds__(256) void cvt_f32_kernel(const void* __restrict__ in,
                                                      float* __restrict__ out, int n,
                                                      const int* __restrict__ flagp) {
    int i = blockIdx.x * 256 + threadIdx.x;
    if (i >= n) return;
    if (flagp[0]) out[i] = __bfloat162float(((const bf16*)in)[i]);
    else out[i] = ((const float*)in)[i];
}

__global__ __launch_bounds__(256) void fill_kernel(bf16* __restrict__ out, long long n) {
    long long i = (long long)blockIdx.x * 256 + threadIdx.x;
    if (i < n) out[i] = __float2bfloat16(1000.0f);
}

// ---------------- CSR build ----------------

__global__ __launch_bounds__(256) void count_kernel(const int* __restrict__ dst,
                                                    int* __restrict__ cnt) {
    int e = blockIdx.x * 256 + threadIdx.x;
    if (e < NE) atomicAdd(&cnt[dst[e]], 1);
}

// 3-phase device-wide exclusive scan over cnt[NN] (1024 elems per block).
#define SCAN_NB ((NN + 1023) / 1024)  // 98

__global__ __launch_bounds__(256) void scan_partial_kernel(const int* __restrict__ cnt,
                                                           int* __restrict__ bsum) {
    __shared__ int lds[256];
    int t = threadIdx.x;
    int base = blockIdx.x * 1024 + t * 4;
    int s = 0;
#pragma unroll
    for (int i = 0; i < 4; ++i) {
        int idx = base + i;
        if (idx < NN) s += cnt[idx];
    }
    lds[t] = s;
    __syncthreads();
    for (int h = 128; h > 0; h >>= 1) {
        if (t < h) lds[t] += lds[t + h];
        __syncthreads();
    }
    if (t == 0) bsum[blockIdx.x] = lds[0];
}

__global__ __launch_bounds__(128) void scan_bsum_kernel(int* __restrict__ bsum,
                                                        int* __restrict__ indptr) {
    __shared__ int lds[128];
    int t = threadIdx.x;
    int v = (t < SCAN_NB) ? bsum[t] : 0;
    lds[t] = v;
    __syncthreads();
    for (int off = 1; off < 128; off <<= 1) {
        int x = (t >= off) ? lds[t - off] : 0;
        __syncthreads();
        lds[t] += x;
        __syncthreads();
    }
    if (t < SCAN_NB) bsum[t] = lds[t] - v;  // exclusive
    if (t == 127) indptr[NN] = lds[127];
}

__global__ __launch_bounds__(256) void scan_apply_kernel(const int* __restrict__ cnt,
                                                         const int* __restrict__ bsum,
                                                         int* __restrict__ indptr,
                                                         int* __restrict__ cursor,
                                                         float* __restrict__ recip) {
    __shared__ int lds[256];
    int t = threadIdx.x;
    int base = blockIdx.x * 1024 + t * 4;
    int c[4];
    int s = 0;
#pragma unroll
    for (int i = 0; i < 4; ++i) {
        int idx = base + i;
        c[i] = (idx < NN) ? cnt[idx] : 0;
        s += c[i];
    }
    lds[t] = s;
    __syncthreads();
    for (int off = 1; off < 256; off <<= 1) {
        int x = (t >= off) ? lds[t - off] : 0;
        __syncthreads();
        lds[t] += x;
        __syncthreads();
    }
    int run = bsum[blockIdx.x] + lds[t] - s;  // exclusive prefix
#pragma unroll
    for (int i = 0; i < 4; ++i) {
        int idx = base + i;
        if (idx < NN) {
            indptr[idx] = run;
            cursor[idx] = run;
            recip[idx] = 1.0f / (float)(c[i] > 1 ? c[i] : 1);
            run += c[i];
        }
    }
}

__global__ __launch_bounds__(256) void scatter_kernel(const int* __restrict__ src,
                                                      const int* __restrict__ dst,
                                                      int* __restrict__ cursor,
                                                      int* __restrict__ csr) {
    int e = blockIdx.x * 256 + threadIdx.x;
    if (e < NE) {
        int d = dst[e];
        int p = atomicAdd(&cursor[d], 1);
        csr[p] = src[e];
    }
}

// ---------------- aggregation (pull over CSR), vectorized 16B/lane ----------------
template <int D, int ADD>
__global__ __launch_bounds__(256) void aggv_kernel(const bf16* __restrict__ u,
                                                   const int* __restrict__ indptr,
                                                   const int* __restrict__ csr,
                                                   const float* __restrict__ recip,
                                                   bf16* __restrict__ out) {
    constexpr int TPR = D / 8;       // threads per node row
    constexpr int NPB = 256 / TPR;   // nodes per block
    const int tid = threadIdx.x;
    const int node = blockIdx.x * NPB + tid / TPR;
    if (node >= NN) return;
    const int c0 = (tid % TPR) * 8;
    const short* ub = (const short*)u + c0;
    const int j0 = indptr[node], j1 = indptr[node + 1];
    float acc[8];
#pragma unroll
    for (int t = 0; t < 8; ++t) acc[t] = 0.f;
    int j = j0;
    for (; j + 3 < j1; j += 4) {
        int s0 = csr[j], s1 = csr[j + 1], s2 = csr[j + 2], s3 = csr[j + 3];
        short8 v0 = *(const short8*)(ub + (size_t)s0 * D);
        short8 v1 = *(const short8*)(ub + (size_t)s1 * D);
        short8 v2 = *(const short8*)(ub + (size_t)s2 * D);
        short8 v3 = *(const short8*)(ub + (size_t)s3 * D);
#pragma unroll
        for (int t = 0; t < 8; ++t)
            acc[t] += (bf2f(v0[t]) + bf2f(v1[t])) + (bf2f(v2[t]) + bf2f(v3[t]));
    }
    for (; j < j1; ++j) {
        short8 v0 = *(const short8*)(ub + (size_t)csr[j] * D);
#pragma unroll
        for (int t = 0; t < 8; ++t) acc[t] += bf2f(v0[t]);
    }
    const float r = recip[node];
    size_t o = (size_t)node * D + c0;
    short8 w;
    if (ADD) {
        short8 prev = *(const short8*)((const short*)out + o);
#pragma unroll
        for (int t = 0; t < 8; ++t) w[t] = f2bf(acc[t] * r + bf2f(prev[t]));
    } else {
#pragma unroll
        for (int t = 0; t < 8; ++t) w[t] = f2bf(acc[t] * r);
    }
    *(short8*)((short*)out + o) = w;
}

// ---------------- bf16 MFMA GEMM:  out = A1@W1^T (+ A2@W2^T) (+ bias) ----------------
__device__ __forceinline__ void gld_lds16(const void* g, void* l) {
    __builtin_amdgcn_global_load_lds(
        (const __attribute__((address_space(1))) unsigned int*)g,
        (__attribute__((address_space(3))) unsigned int*)l, 16, 0, 0);
}

__global__ __launch_bounds__(256) void gemm_kernel(
    const bf16* __restrict__ A1, const bf16* __restrict__ W1, int K1,
    const bf16* __restrict__ A2, const bf16* __restrict__ W2, int K2,
    const float* __restrict__ bias,
    bf16* __restrict__ outB, void* __restrict__ outFinal,
    float* __restrict__ statp,
    const int* __restrict__ flagp,
    int M, int N) {
    // 40KB shared: K-loop uses sA(32KB)+sW(8KB); epilogue reuses first 32KB
    __shared__ alignas(16) char smem[40960];
    char* sA = smem;
    char* sW = smem + 32768;

    const int tid = threadIdx.x;
    const int lane = tid & 63, wv = tid >> 6;
    const int lrow = lane & 15, lq = lane >> 4;

    // XCD-aware bijective swizzle (T1, m204 formula)
    const int nwg = gridDim.x * gridDim.y;
    const int flat = blockIdx.y * gridDim.x + blockIdx.x;
    const int xcd = flat & 7;
    const int rest = flat >> 3;
    const int q = nwg >> 3, r = nwg & 7;
    const int chunk = (xcd < r) ? xcd * (q + 1) : r * (q + 1) + (xcd - r) * q;
    const int newid = chunk + rest;
    const int n0 = (newid % gridDim.x) * 64;
    const int m0 = (newid / gridDim.x) * 256;

    const int isbf = flagp[0];

    f32x4 acc[4][4];
#pragma unroll
    for (int a = 0; a < 4; ++a)
#pragma unroll
        for (int b = 0; b < 4; ++b) acc[a][b] = (f32x4){0.f, 0.f, 0.f, 0.f};

    const int sr = tid >> 3;
    const int scb = (tid & 7) << 4;

#pragma unroll 1
    for (int seg = 0; seg < 2; ++seg) {
        const bf16* Ap = seg ? A2 : A1;
        const bf16* Wp = seg ? W2 : W1;
        const int K = seg ? K2 : K1;
        if (K == 0) continue;
#pragma unroll 1
        for (int k0 = 0; k0 < K; k0 += 64) {
            __syncthreads();
#pragma unroll
            for (int i = 0; i < 8; ++i) {
                int row = i * 32 + sr;
                int gr = m0 + row;
                if (gr >= M) gr = M - 1;  // clamp tail (epilogue guards writes)
                const char* g = (const char*)Ap + ((size_t)gr * K + k0) * 2 +
                                (scb ^ ((row & 7) << 4));
                gld_lds16(g, sA + row * 128 + scb);
            }
#pragma unroll
            for (int i = 0; i < 2; ++i) {
                int row = i * 32 + sr;
                const char* g = (const char*)Wp + ((size_t)(n0 + row) * K + k0) * 2 +
                                (scb ^ ((row & 7) << 4));
                gld_lds16(g, sW + row * 128 + scb);
            }
            __syncthreads();
#pragma unroll
            for (int kh = 0; kh < 2; ++kh) {
                short8 a[4], b[4];
                const int cb = kh * 64 + lq * 16;
#pragma unroll
                for (int mi = 0; mi < 4; ++mi) {
                    int row = wv * 64 + mi * 16 + lrow;
                    a[mi] = *(const short8*)(sA + row * 128 + (cb ^ ((row & 7) << 4)));
                }
#pragma unroll
                for (int ni = 0; ni < 4; ++ni) {
                    int row = ni * 16 + lrow;
                    b[ni] = *(const short8*)(sW + row * 128 + (cb ^ ((row & 7) << 4)));
                }
#pragma unroll
                for (int mi = 0; mi < 4; ++mi)
#pragma unroll
                    for (int ni = 0; ni < 4; ++ni)
                        acc[mi][ni] = __builtin_amdgcn_mfma_f32_16x16x32_bf16(
                            a[mi], b[ni], acc[mi][ni], 0, 0, 0);
            }
        }
    }

    // ---- epilogue ----
    // C/D layout: grow = m0 + wv*64 + mi*16 + lq*4 + r, gcol = n0 + ni*16 + lrow
    // 1) fused BN column stats from acc regs (unchanged semantics)
    if (statp) {
#pragma unroll
        for (int ni = 0; ni < 4; ++ni) {
            int gcol = n0 + ni * 16 + lrow;
            float bv = bias ? bias[gcol] : 0.f;
            float s = 0.f, q2 = 0.f;
#pragma unroll
            for (int mi = 0; mi < 4; ++mi) {
#pragma unroll
                for (int r2 = 0; r2 < 4; ++r2) {
                    int grow = m0 + wv * 64 + mi * 16 + lq * 4 + r2;
                    if (grow < M) {
                        float v = acc[mi][ni][r2] + bv;
                        s += v;
                        q2 += v * v;
                    }
                }
            }
            s += __shfl_xor(s, 16, 64);
            s += __shfl_xor(s, 32, 64);
            q2 += __shfl_xor(q2, 16, 64);
            q2 += __shfl_xor(q2, 32, 64);
            if (lq == 0) {
                atomicAdd(&statp[gcol], s);
                atomicAdd(&statp[N + gcol], q2);
            }
        }
    }
    // 2) LDS-transpose store: scalar 4B/2B stores -> full-line 16B vector stores
    __syncthreads();  // K-loop LDS reads complete before reuse
    const bool f32out = (outFinal != nullptr) && !isbf;
    if (!f32out) {
        // bf16 output: one round, 256x64 bf16 = 32KB
        bf16* dst = outB ? outB : (bf16*)outFinal;
        short* sc = (short*)smem;
#pragma unroll
        for (int ni = 0; ni < 4; ++ni) {
            float bv = bias ? bias[n0 + ni * 16 + lrow] : 0.f;
#pragma unroll
            for (int mi = 0; mi < 4; ++mi) {
                int rl = wv * 64 + mi * 16 + lq * 4;
#pragma unroll
                for (int r2 = 0; r2 < 4; ++r2)
                    sc[(rl + r2) * 64 + ni * 16 + lrow] = f2bf(acc[mi][ni][r2] + bv);
            }
        }
        __syncthreads();
#pragma unroll
        for (int i = 0; i < 8; ++i) {
            int f8 = tid + i * 256;       // short8 index, 8 per row
            int rowl = f8 >> 3;
            int col0 = (f8 & 7) * 8;
            int grow = m0 + rowl;
            if (grow < M)
                *(short8*)((short*)dst + (size_t)grow * N + n0 + col0) =
                    ((const short8*)smem)[f8];
        }
    } else {
        // fp32 output: two rounds of 128 rows (128x64 f32 = 32KB)
        float* dst = (float*)outFinal;
        float* sf = (float*)smem;
#pragma unroll 1
        for (int h = 0; h < 2; ++h) {
            if ((wv >> 1) == h) {
#pragma unroll
                for (int ni = 0; ni < 4; ++ni) {
                    float bv = bias ? bias[n0 + ni * 16 + lrow] : 0.f;
#pragma unroll
                    for (int mi = 0; mi < 4; ++mi) {
                        int rl = (wv & 1) * 64 + mi * 16 + lq * 4;
#pragma unroll
                        for (int r2 = 0; r2 < 4; ++r2)
                            sf[(rl + r2) * 64 + ni * 16 + lrow] = acc[mi][ni][r2] + bv;
                    }
                }
            }
            __syncthreads();
#pragma unroll
            for (int i = 0; i < 8; ++i) {
                int f4 = tid + i * 256;   // float4 index, 16 per row
                int rowl = f4 >> 4;
                int col0 = (f4 & 15) * 4;
                int grow = m0 + h * 128 + rowl;
                if (grow < M)
                    *(float4*)(dst + (size_t)grow * N + n0 + col0) =
                        ((const float4*)smem)[f4];
            }
            __syncthreads();
        }
    }
}

// ---------------- BatchNorm ----------------

__global__ __launch_bounds__(256) void bn_stats_kernel(const bf16* __restrict__ C,
                                                       int ldN,
                                                       float* __restrict__ stats) {
    int N = 1 << ldN;
    int tid = threadIdx.x;
    int c = tid & (N - 1);
    int rsub = tid >> ldN;
    int rstep = 256 >> ldN;
    int r0 = blockIdx.x * 64;
    float s = 0.f, q = 0.f;
    for (int r = r0 + rsub; r < r0 + 64; r += rstep) {
        if (r < NN) {
            float v = __bfloat162float(C[(size_t)r * N + c]);
            s += v;
            q += v * v;
        }
    }
    __shared__ float ls[256], lq[256];
    ls[tid] = s;
    lq[tid] = q;
    __syncthreads();
    for (int half = rstep >> 1; half > 0; half >>= 1) {
        if (rsub < half) {
            ls[tid] += ls[tid + half * N];
            lq[tid] += lq[tid + half * N];
        }
        __syncthreads();
    }
    if (rsub == 0) {
        atomicAdd(&stats[c], ls[tid]);
        atomicAdd(&stats[N + c], lq[tid]);
    }
}

__global__ __launch_bounds__(256) void bn_finalize_kernel(const float* __restrict__ stats,
                                                          const float* __restrict__ g,
                                                          const float* __restrict__ be,
                                                          int N,
                                                          float* __restrict__ scale,
                                                          float* __restrict__ shift) {
    int c = threadIdx.x;
    if (c >= N) return;
    float mean = stats[c] * (1.0f / NN);
    float var = stats[N + c] * (1.0f / NN) - mean * mean;
    var = fmaxf(var, 0.f);
    float sc = g[c] * rsqrtf(var + 1e-5f);
    scale[c] = sc;
    shift[c] = be[c] - mean * sc;
}

// in-place ok; 8 bf16 (16B) per thread
__global__ __launch_bounds__(256) void bn_apply_kernel(const bf16* __restrict__ C,
                                                       const float* __restrict__ scale,
                                                       const float* __restrict__ shift,
                                                       int mask,  // N-1 (N>=64)
                                                       bf16* __restrict__ act,
                                                       long long total8) {
    long long i = (long long)blockIdx.x * 256 + threadIdx.x;
    if (i >= total8) return;
    int c0 = (int)((i * 8) & mask);
    short8 v = ((const short8*)C)[i];
    float4 sc0 = *(const float4*)&scale[c0];
    float4 sc1 = *(const float4*)&scale[c0 + 4];
    float4 sh0 = *(const float4*)&shift[c0];
    float4 sh1 = *(const float4*)&shift[c0 + 4];
    short8 w;
#pragma unroll
    for (int t = 0; t < 4; ++t) {
        float x = bf2f(v[t]) * ((const float*)&sc0)[t] + ((const float*)&sh0)[t];
        w[t] = f2bf(x > 0.f ? x : 0.f);
    }
#pragma unroll
    for (int t = 0; t < 4; ++t) {
        float x = bf2f(v[t + 4]) * ((const float*)&sc1)[t] + ((const float*)&sh1)[t];
        w[t + 4] = f2bf(x > 0.f ? x : 0.f);
    }
    ((short8*)act)[i] = w;
}

// ---------------- host launch ----------------

extern "C" void kernel_launch(void* const* d_in, const int* in_sizes, int n_in,
                              void* d_out, int out_size, void* d_ws, size_t ws_size,
                              hipStream_t stream) {
    const void* x_raw = d_in[0];
    const int* ei = (const int*)d_in[1];
    const int* src = ei;
    const int* dst = ei + NE;

    char* w = (char*)d_ws;
    size_t off = 0;
    auto alloc = [&](size_t bytes) {
        void* p = w + off;
        off = (off + bytes + 255) & ~(size_t)255;
        return p;
    };
    int* flags = (int*)alloc(256);
    int* cnt = (int*)alloc((size_t)NN * 4);
    int* indptr = (int*)alloc((size_t)(NN + 1) * 4);
    int* cursor = (int*)alloc((size_t)NN * 4);
    float* recip = (float*)alloc((size_t)NN * 4);
    int* csr = (int*)alloc((size_t)NE * 4);
    int* bsum = (int*)alloc((size_t)SCAN_NB * 4);
    const int KDIM[5] = {196, 64, 128, 256, 256};   // source K
    const int KPAD[5] = {256, 64, 128, 256, 256};   // padded K (row stride)
    const int NDIM[5] = {64, 128, 256, 256, 576};
    bf16 *Wlb[5], *Wrb[5];
    float *bf_[5], *gf[4], *bef[4];
    for (int i = 0; i < 5; ++i) {
        Wlb[i] = (bf16*)alloc((size_t)KPAD[i] * NDIM[i] * 2);
        Wrb[i] = (bf16*)alloc((size_t)KPAD[i] * NDIM[i] * 2);
        bf_[i] = (float*)alloc((size_t)NDIM[i] * 4);
    }
    for (int i = 0; i < 4; ++i) {
        gf[i] = (float*)alloc((size_t)NDIM[i] * 4);
        bef[i] = (float*)alloc((size_t)NDIM[i] * 4);
    }
    float* stats = (float*)alloc(1408 * 4);
    float* scale = (float*)alloc(256 * 4);
    float* shift = (float*)alloc(256 * 4);
    float *s1 = stats, *s2 = stats + 128, *s3 = stats + 384, *s4 = stats + 896;
    // big slots
    bf16* aggb = (bf16*)alloc((size_t)NN * 256 * 2);  // also holds xb (NN x 256 padded)
    bf16* S1 = (bf16*)alloc((size_t)NN * 256 * 2);
    bf16* S2 = (bf16*)alloc((size_t)NN * 256 * 2);
    bf16* xb = aggb;
    bf16* u1 = S2;

    if (off > ws_size) {
        long long n = (long long)NN * 576;
        fill_kernel<<<(int)((n + 255) / 256), 256, 0, stream>>>((bf16*)d_out, n);
        return;
    }

    hipMemsetAsync(cnt, 0, (size_t)NN * 4, stream);
    hipMemsetAsync(stats, 0, 1408 * 4, stream);

    detect_kernel<<<1, 64, 0, stream>>>((const unsigned int*)x_raw, flags);

    // canonicalize inputs to bf16 (K-padded) / fp32
    {
        int totx = NN * (KPAD[0] >> 2);
        cvt_pad_kernel<<<(totx + 255) / 256, 256, 0, stream>>>(x_raw, xb, NN, 196, 256, flags);
        for (int i = 0; i < 5; ++i) {
            if (KPAD[i] != KDIM[i]) {
                int tot = NDIM[i] * (KPAD[i] >> 2);
                cvt_pad_kernel<<<(tot + 255) / 256, 256, 0, stream>>>(
                    d_in[2 + 3 * i], Wlb[i], NDIM[i], KDIM[i], KPAD[i], flags);
                cvt_pad_kernel<<<(tot + 255) / 256, 256, 0, stream>>>(
                    d_in[3 + 3 * i], Wrb[i], NDIM[i], KDIM[i], KPAD[i], flags);
            } else {
                int nw4 = KDIM[i] * NDIM[i] / 4;
                cvt_bf16_kernel<<<(nw4 + 255) / 256, 256, 0, stream>>>(d_in[2 + 3 * i], Wlb[i], nw4, flags);
                cvt_bf16_kernel<<<(nw4 + 255) / 256, 256, 0, stream>>>(d_in[3 + 3 * i], Wrb[i], nw4, flags);
            }
            cvt_f32_kernel<<<(NDIM[i] + 255) / 256, 256, 0, stream>>>(d_in[4 + 3 * i], bf_[i], NDIM[i], flags);
        }
        for (int i = 0; i < 4; ++i) {
            cvt_f32_kernel<<<(NDIM[i] + 255) / 256, 256, 0, stream>>>(d_in[17 + 2 * i], gf[i], NDIM[i], flags);
            cvt_f32_kernel<<<(NDIM[i] + 255) / 256, 256, 0, stream>>>(d_in[18 + 2 * i], bef[i], NDIM[i], flags);
        }
    }

    count_kernel<<<(NE + 255) / 256, 256, 0, stream>>>(dst, cnt);
    scan_partial_kernel<<<SCAN_NB, 256, 0, stream>>>(cnt, bsum);
    scan_bsum_kernel<<<1, 128, 0, stream>>>(bsum, indptr);
    scan_apply_kernel<<<SCAN_NB, 256, 0, stream>>>(cnt, bsum, indptr, cursor, recip);
    scatter_kernel<<<(NE + 255) / 256, 256, 0, stream>>>(src, dst, cursor, csr);

    const int GM = (NN + 63) / 64;     // bn_stats grid (layer 1 only)
    const int GY = (NN + 255) / 256;   // gemm M-tiles (391)

    // ---- Layer 1: 196(pad 256) -> 64 (aggregate AFTER lin_l)
    gemm_kernel<<<dim3(1, GY), 256, 0, stream>>>(xb, Wlb[0], 256, nullptr, nullptr, 0,
                                                 nullptr, u1, nullptr, nullptr, flags, NN, 64);
    gemm_kernel<<<dim3(1, GY), 256, 0, stream>>>(xb, Wrb[0], 256, nullptr, nullptr, 0,
                                                 bf_[0], S1, nullptr, nullptr, flags, NN, 64);
    aggv_kernel<64, 1><<<NN / 32, 256, 0, stream>>>(u1, indptr, csr, recip, S1);
    bn_stats_kernel<<<GM, 256, 0, stream>>>(S1, 6, s1);
    bn_finalize_kernel<<<1, 256, 0, stream>>>(s1, gf[0], bef[0], 64, scale, shift);
    bn_apply_kernel<<<(NN * 64 / 8 + 255) / 256, 256, 0, stream>>>(S1, scale, shift, 63, S1,
                                                                   (long long)NN * 64 / 8);

    // ---- Layer 2: 64 -> 128  (act1 in S1)
    aggv_kernel<64, 0><<<NN / 32, 256, 0, stream>>>(S1, indptr, csr, recip, aggb);
    gemm_kernel<<<dim3(2, GY), 256, 0, stream>>>(aggb, Wlb[1], 64, S1, Wrb[1], 64,
                                                 bf_[1], S2, nullptr, s2, flags, NN, 128);
    bn_finalize_kernel<<<1, 256, 0, stream>>>(s2, gf[1], bef[1], 128, scale, shift);
    bn_apply_kernel<<<(NN * 128 / 8 + 255) / 256, 256, 0, stream>>>(S2, scale, shift, 127, S2,
                                                                    (long long)NN * 128 / 8);

    // ---- Layer 3: 128 -> 256  (act2 in S2)
    aggv_kernel<128, 0><<<NN / 16, 256, 0, stream>>>(S2, indptr, csr, recip, aggb);
    gemm_kernel<<<dim3(4, GY), 256, 0, stream>>>(aggb, Wlb[2], 128, S2, Wrb[2], 128,
                                                 bf_[2], S1, nullptr, s3, flags, NN, 256);
    bn_finalize_kernel<<<1, 256, 0, stream>>>(s3, gf[2], bef[2], 256, scale, shift);
    bn_apply_kernel<<<(NN * 256 / 8 + 255) / 256, 256, 0, stream>>>(S1, scale, shift, 255, S1,
                                                                    (long long)NN * 256 / 8);

    // ---- Layer 4: 256 -> 256  (act3 in S1)
    aggv_kernel<256, 0><<<NN / 8, 256, 0, stream>>>(S1, indptr, csr, recip, aggb);
    gemm_kernel<<<dim3(4, GY), 256, 0, stream>>>(aggb, Wlb[3], 256, S1, Wrb[3], 256,
                                                 bf_[3], S2, nullptr, s4, flags, NN, 256);
    bn_finalize_kernel<<<1, 256, 0, stream>>>(s4, gf[3], bef[3], 256, scale, shift);
    bn_apply_kernel<<<(NN * 256 / 8 + 255) / 256, 256, 0, stream>>>(S2, scale, shift, 255, S2,
                                                                    (long long)NN * 256 / 8);

    // ---- Layer 5: 256 -> 576, no BN/ReLU, write d_out (bf16 or fp32 per flag)
    aggv_kernel<256, 0><<<NN / 8, 256, 0, stream>>>(S2, indptr, csr, recip, aggb);
    gemm_kernel<<<dim3(9, GY), 256, 0, stream>>>(aggb, Wlb[4], 256, S2, Wrb[4], 256,
                                                 bf_[4], nullptr, d_out, nullptr, flags, NN, 576);
}

// Round 6
// 1268.001 us; speedup vs baseline: 3.2587x; 1.0327x over previous
//
#include <hip/hip_runtime.h>
#include <hip/hip_bf16.h>

typedef __hip_bfloat16 bf16;
typedef __attribute__((ext_vector_type(8))) short short8;
typedef __attribute__((ext_vector_type(4))) float f32x4;

#define NN 100000
#define NE 1600000

__device__ __forceinline__ float bf2f(short s) {
    return __uint_as_float(((unsigned int)(unsigned short)s) << 16);
}
__device__ __forceinline__ short f2bf(float f) {
    union { bf16 b; short s; } u;
    u.b = __float2bfloat16(f);
    return u.s;
}

// ---------------- dtype detection ----------------
__global__ void detect_kernel(const unsigned int* __restrict__ x, int* __restrict__ flags) {
    __shared__ int s;
    if (threadIdx.x == 0) s = 0;
    __syncthreads();
    int c = 0;
    for (int j = 0; j < 4; ++j) {
        unsigned int w = x[threadIdx.x * 4 + j];
        unsigned int e = (w >> 7) & 0xFF;
        if (e >= 100 && e <= 141) c++;
    }
    atomicAdd(&s, c);
    __syncthreads();
    if (threadIdx.x == 0) flags[0] = (s > 128) ? 1 : 0;
}

// ---------------- input canonicalization ----------------
// rows x sk (src) -> rows x dk (dst, zero-padded cols sk..dk). sk%4==0, dk%4==0.
__global__ __launch_bounds__(256) void cvt_pad_kernel(const void* __restrict__ in,
                                                      bf16* __restrict__ out,
                                                      int rows, int sk, int dk,
                                                      const int* __restrict__ flagp) {
    int i = blockIdx.x * 256 + threadIdx.x;
    int g4 = dk >> 2;
    if (i >= rows * g4) return;
    int row = i / g4;
    int c = (i - row * g4) * 4;
    uint2 w;
    w.x = 0u; w.y = 0u;
    if (c < sk) {
        if (flagp[0]) {
            w = *(const uint2*)((const char*)in + ((size_t)row * sk + c) * 2);
        } else {
            const float* f = (const float*)((const char*)in + ((size_t)row * sk + c) * 4);
            union { bf16 t[4]; uint2 u; } pk;
            pk.t[0] = __float2bfloat16(f[0]);
            pk.t[1] = __float2bfloat16(f[1]);
            pk.t[2] = __float2bfloat16(f[2]);
            pk.t[3] = __float2bfloat16(f[3]);
            w = pk.u;
        }
    }
    *(uint2*)((char*)out + ((size_t)row * dk + c) * 2) = w;
}

// batched weight conversion: blockIdx.y = job
struct WJobs {
    const void* src[10];
    bf16* dst[10];
    int rows[10];
    int sk[10];
    int dk[10];
};
__global__ __launch_bounds__(256) void cvt_pad_multi(WJobs J, const int* __restrict__ flagp) {
    int j = blockIdx.y;
    int g4 = J.dk[j] >> 2;
    int tot = J.rows[j] * g4;
    int i = blockIdx.x * 256 + threadIdx.x;
    if (i >= tot) return;
    int row = i / g4;
    int c = (i - row * g4) * 4;
    int sk = J.sk[j];
    uint2 w;
    w.x = 0u; w.y = 0u;
    if (c < sk) {
        if (flagp[0]) {
            w = *(const uint2*)((const char*)J.src[j] + ((size_t)row * sk + c) * 2);
        } else {
            const float* f = (const float*)((const char*)J.src[j] + ((size_t)row * sk + c) * 4);
            union { bf16 t[4]; uint2 u; } pk;
            pk.t[0] = __float2bfloat16(f[0]);
            pk.t[1] = __float2bfloat16(f[1]);
            pk.t[2] = __float2bfloat16(f[2]);
            pk.t[3] = __float2bfloat16(f[3]);
            w = pk.u;
        }
    }
    *(uint2*)((char*)J.dst[j] + ((size_t)row * J.dk[j] + c) * 2) = w;
}

// batched small-vector f32 conversion: blockIdx.x = job
struct VJobs {
    const void* src[13];
    float* dst[13];
    int n[13];
};
__global__ __launch_bounds__(576) void cvt_f32_multi(VJobs J, const int* __restrict__ flagp) {
    int j = blockIdx.x;
    int c = threadIdx.x;
    if (c >= J.n[j]) return;
    float v;
    if (flagp[0]) v = __bfloat162float(((const bf16*)J.src[j])[c]);
    else v = ((const float*)J.src[j])[c];
    J.dst[j][c] = v;
}

__global__ __launch_bounds__(256) void fill_kernel(bf16* __restrict__ out, long long n) {
    long long i = (long long)blockIdx.x * 256 + threadIdx.x;
    if (i < n) out[i] = __float2bfloat16(1000.0f);
}

// ---------------- CSR build ----------------

__global__ __launch_bounds__(256) void count_kernel(const int* __restrict__ dst,
                                                    int* __restrict__ cnt) {
    int e = blockIdx.x * 256 + threadIdx.x;
    if (e < NE) atomicAdd(&cnt[dst[e]], 1);
}

// 3-phase device-wide exclusive scan over cnt[NN] (1024 elems per block).
#define SCAN_NB ((NN + 1023) / 1024)  // 98

__global__ __launch_bounds__(256) void scan_partial_kernel(const int* __restrict__ cnt,
                                                           int* __restrict__ bsum) {
    __shared__ int lds[256];
    int t = threadIdx.x;
    int base = blockIdx.x * 1024 + t * 4;
    int s = 0;
#pragma unroll
    for (int i = 0; i < 4; ++i) {
        int idx = base + i;
        if (idx < NN) s += cnt[idx];
    }
    lds[t] = s;
    __syncthreads();
    for (int h = 128; h > 0; h >>= 1) {
        if (t < h) lds[t] += lds[t + h];
        __syncthreads();
    }
    if (t == 0) bsum[blockIdx.x] = lds[0];
}

__global__ __launch_bounds__(128) void scan_bsum_kernel(int* __restrict__ bsum,
                                                        int* __restrict__ indptr) {
    __shared__ int lds[128];
    int t = threadIdx.x;
    int v = (t < SCAN_NB) ? bsum[t] : 0;
    lds[t] = v;
    __syncthreads();
    for (int off = 1; off < 128; off <<= 1) {
        int x = (t >= off) ? lds[t - off] : 0;
        __syncthreads();
        lds[t] += x;
        __syncthreads();
    }
    if (t < SCAN_NB) bsum[t] = lds[t] - v;  // exclusive
    if (t == 127) indptr[NN] = lds[127];
}

__global__ __launch_bounds__(256) void scan_apply_kernel(const int* __restrict__ cnt,
                                                         const int* __restrict__ bsum,
                                                         int* __restrict__ indptr,
                                                         int* __restrict__ cursor,
                                                         float* __restrict__ recip) {
    __shared__ int lds[256];
    int t = threadIdx.x;
    int base = blockIdx.x * 1024 + t * 4;
    int c[4];
    int s = 0;
#pragma unroll
    for (int i = 0; i < 4; ++i) {
        int idx = base + i;
        c[i] = (idx < NN) ? cnt[idx] : 0;
        s += c[i];
    }
    lds[t] = s;
    __syncthreads();
    for (int off = 1; off < 256; off <<= 1) {
        int x = (t >= off) ? lds[t - off] : 0;
        __syncthreads();
        lds[t] += x;
        __syncthreads();
    }
    int run = bsum[blockIdx.x] + lds[t] - s;  // exclusive prefix
#pragma unroll
    for (int i = 0; i < 4; ++i) {
        int idx = base + i;
        if (idx < NN) {
            indptr[idx] = run;
            cursor[idx] = run;
            recip[idx] = 1.0f / (float)(c[i] > 1 ? c[i] : 1);
            run += c[i];
        }
    }
}

__global__ __launch_bounds__(256) void scatter_kernel(const int* __restrict__ src,
                                                      const int* __restrict__ dst,
                                                      int* __restrict__ cursor,
                                                      int* __restrict__ csr) {
    int e = blockIdx.x * 256 + threadIdx.x;
    if (e < NE) {
        int d = dst[e];
        int p = atomicAdd(&cursor[d], 1);
        csr[p] = src[e];
    }
}

// ---------------- aggregation (pull over CSR), vectorized 16B/lane ----------------
template <int D, int ADD>
__global__ __launch_bounds__(256) void aggv_kernel(const bf16* __restrict__ u,
                                                   const int* __restrict__ indptr,
                                                   const int* __restrict__ csr,
                                                   const float* __restrict__ recip,
                                                   bf16* __restrict__ out) {
    constexpr int TPR = D / 8;       // threads per node row
    constexpr int NPB = 256 / TPR;   // nodes per block
    const int tid = threadIdx.x;
    const int node = blockIdx.x * NPB + tid / TPR;
    if (node >= NN) return;
    const int c0 = (tid % TPR) * 8;
    const short* ub = (const short*)u + c0;
    const int j0 = indptr[node], j1 = indptr[node + 1];
    float acc[8];
#pragma unroll
    for (int t = 0; t < 8; ++t) acc[t] = 0.f;
    int j = j0;
    for (; j + 3 < j1; j += 4) {
        int s0 = csr[j], s1 = csr[j + 1], s2 = csr[j + 2], s3 = csr[j + 3];
        short8 v0 = *(const short8*)(ub + (size_t)s0 * D);
        short8 v1 = *(const short8*)(ub + (size_t)s1 * D);
        short8 v2 = *(const short8*)(ub + (size_t)s2 * D);
        short8 v3 = *(const short8*)(ub + (size_t)s3 * D);
#pragma unroll
        for (int t = 0; t < 8; ++t)
            acc[t] += (bf2f(v0[t]) + bf2f(v1[t])) + (bf2f(v2[t]) + bf2f(v3[t]));
    }
    for (; j < j1; ++j) {
        short8 v0 = *(const short8*)(ub + (size_t)csr[j] * D);
#pragma unroll
        for (int t = 0; t < 8; ++t) acc[t] += bf2f(v0[t]);
    }
    const float r = recip[node];
    size_t o = (size_t)node * D + c0;
    short8 w;
    if (ADD) {
        short8 prev = *(const short8*)((const short*)out + o);
#pragma unroll
        for (int t = 0; t < 8; ++t) w[t] = f2bf(acc[t] * r + bf2f(prev[t]));
    } else {
#pragma unroll
        for (int t = 0; t < 8; ++t) w[t] = f2bf(acc[t] * r);
    }
    *(short8*)((short*)out + o) = w;
}

// ---------------- bf16 MFMA GEMM:  out = A1@W1^T (+ A2@W2^T) (+ bias) ----------------
// Column-split output: global cols [0,Nsplit) -> outB (row stride Nsplit),
// cols [Nsplit,N) -> outB2 (row stride N-Nsplit). Normal layers: Nsplit=N.
__device__ __forceinline__ void gld_lds16(const void* g, void* l) {
    __builtin_amdgcn_global_load_lds(
        (const __attribute__((address_space(1))) unsigned int*)g,
        (__attribute__((address_space(3))) unsigned int*)l, 16, 0, 0);
}

__global__ __launch_bounds__(256) void gemm_kernel(
    const bf16* __restrict__ A1, const bf16* __restrict__ W1, int K1,
    const bf16* __restrict__ A2, const bf16* __restrict__ W2, int K2,
    const float* __restrict__ bias,
    bf16* __restrict__ outB, bf16* __restrict__ outB2, int Nsplit,
    void* __restrict__ outFinal,
    float* __restrict__ statp,
    const int* __restrict__ flagp,
    int M, int N) {
    // 40KB shared: K-loop uses sA(32KB)+sW(8KB); epilogue reuses first 32KB
    __shared__ alignas(16) char smem[40960];
    char* sA = smem;
    char* sW = smem + 32768;

    const int tid = threadIdx.x;
    const int lane = tid & 63, wv = tid >> 6;
    const int lrow = lane & 15, lq = lane >> 4;

    // XCD-aware bijective swizzle (T1, m204 formula)
    const int nwg = gridDim.x * gridDim.y;
    const int flat = blockIdx.y * gridDim.x + blockIdx.x;
    const int xcd = flat & 7;
    const int rest = flat >> 3;
    const int q = nwg >> 3, r = nwg & 7;
    const int chunk = (xcd < r) ? xcd * (q + 1) : r * (q + 1) + (xcd - r) * q;
    const int newid = chunk + rest;
    const int n0 = (newid % gridDim.x) * 64;
    const int m0 = (newid / gridDim.x) * 256;

    const int isbf = flagp[0];

    f32x4 acc[4][4];
#pragma unroll
    for (int a = 0; a < 4; ++a)
#pragma unroll
        for (int b = 0; b < 4; ++b) acc[a][b] = (f32x4){0.f, 0.f, 0.f, 0.f};

    const int sr = tid >> 3;
    const int scb = (tid & 7) << 4;

#pragma unroll 1
    for (int seg = 0; seg < 2; ++seg) {
        const bf16* Ap = seg ? A2 : A1;
        const bf16* Wp = seg ? W2 : W1;
        const int K = seg ? K2 : K1;
        if (K == 0) continue;
#pragma unroll 1
        for (int k0 = 0; k0 < K; k0 += 64) {
            __syncthreads();
#pragma unroll
            for (int i = 0; i < 8; ++i) {
                int row = i * 32 + sr;
                int gr = m0 + row;
                if (gr >= M) gr = M - 1;  // clamp tail (epilogue guards writes)
                const char* g = (const char*)Ap + ((size_t)gr * K + k0) * 2 +
                                (scb ^ ((row & 7) << 4));
                gld_lds16(g, sA + row * 128 + scb);
            }
#pragma unroll
            for (int i = 0; i < 2; ++i) {
                int row = i * 32 + sr;
                const char* g = (const char*)Wp + ((size_t)(n0 + row) * K + k0) * 2 +
                                (scb ^ ((row & 7) << 4));
                gld_lds16(g, sW + row * 128 + scb);
            }
            __syncthreads();
#pragma unroll
            for (int kh = 0; kh < 2; ++kh) {
                short8 a[4], b[4];
                const int cb = kh * 64 + lq * 16;
#pragma unroll
                for (int mi = 0; mi < 4; ++mi) {
                    int row = wv * 64 + mi * 16 + lrow;
                    a[mi] = *(const short8*)(sA + row * 128 + (cb ^ ((row & 7) << 4)));
                }
#pragma unroll
                for (int ni = 0; ni < 4; ++ni) {
                    int row = ni * 16 + lrow;
                    b[ni] = *(const short8*)(sW + row * 128 + (cb ^ ((row & 7) << 4)));
                }
#pragma unroll
                for (int mi = 0; mi < 4; ++mi)
#pragma unroll
                    for (int ni = 0; ni < 4; ++ni)
                        acc[mi][ni] = __builtin_amdgcn_mfma_f32_16x16x32_bf16(
                            a[mi], b[ni], acc[mi][ni], 0, 0, 0);
            }
        }
    }

    // ---- epilogue ----
    // C/D layout: grow = m0 + wv*64 + mi*16 + lq*4 + r, gcol = n0 + ni*16 + lrow
    // 1) fused BN column stats from acc regs
    if (statp) {
#pragma unroll
        for (int ni = 0; ni < 4; ++ni) {
            int gcol = n0 + ni * 16 + lrow;
            float bv = bias ? bias[gcol] : 0.f;
            float s = 0.f, q2 = 0.f;
#pragma unroll
            for (int mi = 0; mi < 4; ++mi) {
#pragma unroll
                for (int r2 = 0; r2 < 4; ++r2) {
                    int grow = m0 + wv * 64 + mi * 16 + lq * 4 + r2;
                    if (grow < M) {
                        float v = acc[mi][ni][r2] + bv;
                        s += v;
                        q2 += v * v;
                    }
                }
            }
            s += __shfl_xor(s, 16, 64);
            s += __shfl_xor(s, 32, 64);
            q2 += __shfl_xor(q2, 16, 64);
            q2 += __shfl_xor(q2, 32, 64);
            if (lq == 0) {
                atomicAdd(&statp[gcol], s);
                atomicAdd(&statp[N + gcol], q2);
            }
        }
    }
    // 2) LDS-transpose store: full-line 16B vector stores
    __syncthreads();  // K-loop LDS reads complete before reuse
    const bool f32out = (outFinal != nullptr) && !isbf;
    if (!f32out) {
        // bf16 output: one round, 256x64 bf16 = 32KB
        bf16* dst = outB ? outB : (bf16*)outFinal;
        short* sc = (short*)smem;
#pragma unroll
        for (int ni = 0; ni < 4; ++ni) {
            float bv = bias ? bias[n0 + ni * 16 + lrow] : 0.f;
#pragma unroll
            for (int mi = 0; mi < 4; ++mi) {
                int rl = wv * 64 + mi * 16 + lq * 4;
#pragma unroll
                for (int r2 = 0; r2 < 4; ++r2)
                    sc[(rl + r2) * 64 + ni * 16 + lrow] = f2bf(acc[mi][ni][r2] + bv);
            }
        }
        __syncthreads();
#pragma unroll
        for (int i = 0; i < 8; ++i) {
            int f8 = tid + i * 256;       // short8 index, 8 per row
            int rowl = f8 >> 3;
            int col0 = (f8 & 7) * 8;
            int grow = m0 + rowl;
            int gcol = n0 + col0;
            if (grow < M) {
                short8 v = ((const short8*)smem)[f8];
                if (gcol < Nsplit)
                    *(short8*)((short*)dst + (size_t)grow * Nsplit + gcol) = v;
                else
                    *(short8*)((short*)outB2 + (size_t)grow * (N - Nsplit) +
                               (gcol - Nsplit)) = v;
            }
        }
    } else {
        // fp32 output: two rounds of 128 rows (128x64 f32 = 32KB)
        float* dst = (float*)outFinal;
        float* sf = (float*)smem;
#pragma unroll 1
        for (int h = 0; h < 2; ++h) {
            if ((wv >> 1) == h) {
#pragma unroll
                for (int ni = 0; ni < 4; ++ni) {
                    float bv = bias ? bias[n0 + ni * 16 + lrow] : 0.f;
#pragma unroll
                    for (int mi = 0; mi < 4; ++mi) {
                        int rl = (wv & 1) * 64 + mi * 16 + lq * 4;
#pragma unroll
                        for (int r2 = 0; r2 < 4; ++r2)
                            sf[(rl + r2) * 64 + ni * 16 + lrow] = acc[mi][ni][r2] + bv;
                    }
                }
            }
            __syncthreads();
#pragma unroll
            for (int i = 0; i < 8; ++i) {
                int f4 = tid + i * 256;   // float4 index, 16 per row
                int rowl = f4 >> 4;
                int col0 = (f4 & 15) * 4;
                int grow = m0 + h * 128 + rowl;
                if (grow < M)
                    *(float4*)(dst + (size_t)grow * N + n0 + col0) =
                        ((const float4*)smem)[f4];
            }
            __syncthreads();
        }
    }
}

// ---------------- BatchNorm ----------------

__global__ __launch_bounds__(256) void bn_stats_kernel(const bf16* __restrict__ C,
                                                       int ldN,
                                                       float* __restrict__ stats) {
    int N = 1 << ldN;
    int tid = threadIdx.x;
    int c = tid & (N - 1);
    int rsub = tid >> ldN;
    int rstep = 256 >> ldN;
    int r0 = blockIdx.x * 64;
    float s = 0.f, q = 0.f;
    for (int r = r0 + rsub; r < r0 + 64; r += rstep) {
        if (r < NN) {
            float v = __bfloat162float(C[(size_t)r * N + c]);
            s += v;
            q += v * v;
        }
    }
    __shared__ float ls[256], lq[256];
    ls[tid] = s;
    lq[tid] = q;
    __syncthreads();
    for (int half = rstep >> 1; half > 0; half >>= 1) {
        if (rsub < half) {
            ls[tid] += ls[tid + half * N];
            lq[tid] += lq[tid + half * N];
        }
        __syncthreads();
    }
    if (rsub == 0) {
        atomicAdd(&stats[c], ls[tid]);
        atomicAdd(&stats[N + c], lq[tid]);
    }
}

__global__ __launch_bounds__(256) void bn_finalize_kernel(const float* __restrict__ stats,
                                                          const float* __restrict__ g,
                                                          const float* __restrict__ be,
                                                          int N,
                                                          float* __restrict__ scale,
                                                          float* __restrict__ shift) {
    int c = threadIdx.x;
    if (c >= N) return;
    float mean = stats[c] * (1.0f / NN);
    float var = stats[N + c] * (1.0f / NN) - mean * mean;
    var = fmaxf(var, 0.f);
    float sc = g[c] * rsqrtf(var + 1e-5f);
    scale[c] = sc;
    shift[c] = be[c] - mean * sc;
}

// in-place ok; 8 bf16 (16B) per thread
__global__ __launch_bounds__(256) void bn_apply_kernel(const bf16* __restrict__ C,
                                                       const float* __restrict__ scale,
                                                       const float* __restrict__ shift,
                                                       int mask,  // N-1 (N>=64)
                                                       bf16* __restrict__ act,
                                                       long long total8) {
    long long i = (long long)blockIdx.x * 256 + threadIdx.x;
    if (i >= total8) return;
    int c0 = (int)((i * 8) & mask);
    short8 v = ((const short8*)C)[i];
    float4 sc0 = *(const float4*)&scale[c0];
    float4 sc1 = *(const float4*)&scale[c0 + 4];
    float4 sh0 = *(const float4*)&shift[c0];
    float4 sh1 = *(const float4*)&shift[c0 + 4];
    short8 w;
#pragma unroll
    for (int t = 0; t < 4; ++t) {
        float x = bf2f(v[t]) * ((const float*)&sc0)[t] + ((const float*)&sh0)[t];
        w[t] = f2bf(x > 0.f ? x : 0.f);
    }
#pragma unroll
    for (int t = 0; t < 4; ++t) {
        float x = bf2f(v[t + 4]) * ((const float*)&sc1)[t] + ((const float*)&sh1)[t];
        w[t + 4] = f2bf(x > 0.f ? x : 0.f);
    }
    ((short8*)act)[i] = w;
}

// ---------------- host launch ----------------

extern "C" void kernel_launch(void* const* d_in, const int* in_sizes, int n_in,
                              void* d_out, int out_size, void* d_ws, size_t ws_size,
                              hipStream_t stream) {
    const void* x_raw = d_in[0];
    const int* ei = (const int*)d_in[1];
    const int* src = ei;
    const int* dst = ei + NE;

    char* w = (char*)d_ws;
    size_t off = 0;
    auto alloc = [&](size_t bytes) {
        void* p = w + off;
        off = (off + bytes + 255) & ~(size_t)255;
        return p;
    };
    int* flags = (int*)alloc(256);
    int* cnt = (int*)alloc((size_t)NN * 4);
    int* indptr = (int*)alloc((size_t)(NN + 1) * 4);
    int* cursor = (int*)alloc((size_t)NN * 4);
    float* recip = (float*)alloc((size_t)NN * 4);
    int* csr = (int*)alloc((size_t)NE * 4);
    int* bsum = (int*)alloc((size_t)SCAN_NB * 4);
    const int KDIM[5] = {196, 64, 128, 256, 256};   // source K
    const int KPAD[5] = {256, 64, 128, 256, 256};   // padded K (row stride)
    const int NDIM[5] = {64, 128, 256, 256, 576};
    bf16 *Wlb[5], *Wrb[5];
    float *bf_[5], *gf[4], *bef[4];
    for (int i = 0; i < 5; ++i) {
        // NOTE: Wlb[i] and Wrb[i] are contiguous (sizes are 256-aligned):
        // layer-1 fused gemm relies on Wlb[0]..Wrb[0] forming a 128x256 matrix.
        Wlb[i] = (bf16*)alloc((size_t)KPAD[i] * NDIM[i] * 2);
        Wrb[i] = (bf16*)alloc((size_t)KPAD[i] * NDIM[i] * 2);
        bf_[i] = (float*)alloc((size_t)NDIM[i] * 4);
    }
    for (int i = 0; i < 4; ++i) {
        gf[i] = (float*)alloc((size_t)NDIM[i] * 4);
        bef[i] = (float*)alloc((size_t)NDIM[i] * 4);
    }
    float* bias1cat = (float*)alloc(128 * 4);  // [0..63]=0, [64..127]=b1
    float* stats = (float*)alloc(1408 * 4);
    float* scale = (float*)alloc(256 * 4);
    float* shift = (float*)alloc(256 * 4);
    float *s1 = stats, *s2 = stats + 128, *s3 = stats + 384, *s4 = stats + 896;
    // big slots
    bf16* aggb = (bf16*)alloc((size_t)NN * 256 * 2);  // also holds xb (NN x 256 padded)
    bf16* S1 = (bf16*)alloc((size_t)NN * 256 * 2);
    bf16* S2 = (bf16*)alloc((size_t)NN * 256 * 2);
    bf16* xb = aggb;
    bf16* u1 = S2;

    if (off > ws_size) {
        long long n = (long long)NN * 576;
        fill_kernel<<<(int)((n + 255) / 256), 256, 0, stream>>>((bf16*)d_out, n);
        return;
    }

    hipMemsetAsync(cnt, 0, (size_t)NN * 4, stream);
    hipMemsetAsync(stats, 0, 1408 * 4, stream);
    hipMemsetAsync(bias1cat, 0, 64 * 4, stream);

    detect_kernel<<<1, 64, 0, stream>>>((const unsigned int*)x_raw, flags);

    // canonicalize inputs: x (large, own launch) + batched weights + batched vectors
    {
        int totx = NN * (KPAD[0] >> 2);
        cvt_pad_kernel<<<(totx + 255) / 256, 256, 0, stream>>>(x_raw, xb, NN, 196, 256, flags);

        WJobs wj;
        int maxb = 0;
        for (int i = 0; i < 5; ++i) {
            wj.src[2 * i] = d_in[2 + 3 * i];
            wj.dst[2 * i] = Wlb[i];
            wj.src[2 * i + 1] = d_in[3 + 3 * i];
            wj.dst[2 * i + 1] = Wrb[i];
            wj.rows[2 * i] = wj.rows[2 * i + 1] = NDIM[i];
            wj.sk[2 * i] = wj.sk[2 * i + 1] = KDIM[i];
            wj.dk[2 * i] = wj.dk[2 * i + 1] = KPAD[i];
            int nb = (NDIM[i] * (KPAD[i] >> 2) + 255) / 256;
            if (nb > maxb) maxb = nb;
        }
        cvt_pad_multi<<<dim3(maxb, 10), 256, 0, stream>>>(wj, flags);

        VJobs vj;
        vj.src[0] = d_in[4];  vj.dst[0] = bias1cat + 64; vj.n[0] = 64;  // b1
        for (int i = 1; i < 5; ++i) {
            vj.src[i] = d_in[4 + 3 * i];
            vj.dst[i] = bf_[i];
            vj.n[i] = NDIM[i];
        }
        for (int i = 0; i < 4; ++i) {
            vj.src[5 + i] = d_in[17 + 2 * i];
            vj.dst[5 + i] = gf[i];
            vj.n[5 + i] = NDIM[i];
            vj.src[9 + i] = d_in[18 + 2 * i];
            vj.dst[9 + i] = bef[i];
            vj.n[9 + i] = NDIM[i];
        }
        cvt_f32_multi<<<13, 576, 0, stream>>>(vj, flags);
    }

    count_kernel<<<(NE + 255) / 256, 256, 0, stream>>>(dst, cnt);
    scan_partial_kernel<<<SCAN_NB, 256, 0, stream>>>(cnt, bsum);
    scan_bsum_kernel<<<1, 128, 0, stream>>>(bsum, indptr);
    scan_apply_kernel<<<SCAN_NB, 256, 0, stream>>>(cnt, bsum, indptr, cursor, recip);
    scatter_kernel<<<(NE + 255) / 256, 256, 0, stream>>>(src, dst, cursor, csr);

    const int GM = (NN + 63) / 64;     // bn_stats grid (layer 1 only)
    const int GY = (NN + 255) / 256;   // gemm M-tiles (391)

    // ---- Layer 1: 196(pad 256) -> 64, FUSED dual-output gemm:
    // Wcat = [Wl1; Wr1] (128x256, contiguous), cols 0-63 -> u1 (no bias),
    // cols 64-127 -> S1 (+b1). Aggregation AFTER lin_l.
    gemm_kernel<<<dim3(2, GY), 256, 0, stream>>>(xb, Wlb[0], 256, nullptr, nullptr, 0,
                                                 bias1cat, u1, S1, 64,
                                                 nullptr, nullptr, flags, NN, 128);
    aggv_kernel<64, 1><<<NN / 32, 256, 0, stream>>>(u1, indptr, csr, recip, S1);
    bn_stats_kernel<<<GM, 256, 0, stream>>>(S1, 6, s1);
    bn_finalize_kernel<<<1, 256, 0, stream>>>(s1, gf[0], bef[0], 64, scale, shift);
    bn_apply_kernel<<<(NN * 64 / 8 + 255) / 256, 256, 0, stream>>>(S1, scale, shift, 63, S1,
                                                                   (long long)NN * 64 / 8);

    // ---- Layer 2: 64 -> 128  (act1 in S1)
    aggv_kernel<64, 0><<<NN / 32, 256, 0, stream>>>(S1, indptr, csr, recip, aggb);
    gemm_kernel<<<dim3(2, GY), 256, 0, stream>>>(aggb, Wlb[1], 64, S1, Wrb[1], 64,
                                                 bf_[1], S2, nullptr, 128,
                                                 nullptr, s2, flags, NN, 128);
    bn_finalize_kernel<<<1, 256, 0, stream>>>(s2, gf[1], bef[1], 128, scale, shift);
    bn_apply_kernel<<<(NN * 128 / 8 + 255) / 256, 256, 0, stream>>>(S2, scale, shift, 127, S2,
                                                                    (long long)NN * 128 / 8);

    // ---- Layer 3: 128 -> 256  (act2 in S2)
    aggv_kernel<128, 0><<<NN / 16, 256, 0, stream>>>(S2, indptr, csr, recip, aggb);
    gemm_kernel<<<dim3(4, GY), 256, 0, stream>>>(aggb, Wlb[2], 128, S2, Wrb[2], 128,
                                                 bf_[2], S1, nullptr, 256,
                                                 nullptr, s3, flags, NN, 256);
    bn_finalize_kernel<<<1, 256, 0, stream>>>(s3, gf[2], bef[2], 256, scale, shift);
    bn_apply_kernel<<<(NN * 256 / 8 + 255) / 256, 256, 0, stream>>>(S1, scale, shift, 255, S1,
                                                                    (long long)NN * 256 / 8);

    // ---- Layer 4: 256 -> 256  (act3 in S1)
    aggv_kernel<256, 0><<<NN / 8, 256, 0, stream>>>(S1, indptr, csr, recip, aggb);
    gemm_kernel<<<dim3(4, GY), 256, 0, stream>>>(aggb, Wlb[3], 256, S1, Wrb[3], 256,
                                                 bf_[3], S2, nullptr, 256,
                                                 nullptr, s4, flags, NN, 256);
    bn_finalize_kernel<<<1, 256, 0, stream>>>(s4, gf[3], bef[3], 256, scale, shift);
    bn_apply_kernel<<<(NN * 256 / 8 + 255) / 256, 256, 0, stream>>>(S2, scale, shift, 255, S2,
                                                                    (long long)NN * 256 / 8);

    // ---- Layer 5: 256 -> 576, no BN/ReLU, write d_out (bf16 or fp32 per flag)
    aggv_kernel<256, 0><<<NN / 8, 256, 0, stream>>>(S2, indptr, csr, recip, aggb);
    gemm_kernel<<<dim3(9, GY), 256, 0, stream>>>(aggb, Wlb[4], 256, S2, Wrb[4], 256,
                                                 bf_[4], nullptr, nullptr, 576,
                                                 d_out, nullptr, flags, NN, 576);
}

// Round 7
// 1247.458 us; speedup vs baseline: 3.3123x; 1.0165x over previous
//
#include <hip/hip_runtime.h>
#include <hip/hip_bf16.h>

typedef __hip_bfloat16 bf16;
typedef __attribute__((ext_vector_type(8))) short short8;
typedef __attribute__((ext_vector_type(4))) float f32x4;

#define NN 100000
#define NE 1600000

__device__ __forceinline__ float bf2f(short s) {
    return __uint_as_float(((unsigned int)(unsigned short)s) << 16);
}
__device__ __forceinline__ short f2bf(float f) {
    union { bf16 b; short s; } u;
    u.b = __float2bfloat16(f);
    return u.s;
}

// ---------------- dtype detection ----------------
__global__ void detect_kernel(const unsigned int* __restrict__ x, int* __restrict__ flags) {
    __shared__ int s;
    if (threadIdx.x == 0) s = 0;
    __syncthreads();
    int c = 0;
    for (int j = 0; j < 4; ++j) {
        unsigned int w = x[threadIdx.x * 4 + j];
        unsigned int e = (w >> 7) & 0xFF;
        if (e >= 100 && e <= 141) c++;
    }
    atomicAdd(&s, c);
    __syncthreads();
    if (threadIdx.x == 0) flags[0] = (s > 128) ? 1 : 0;
}

// ---------------- input canonicalization ----------------
// rows x sk (src) -> rows x dk (dst, zero-padded cols sk..dk). sk%4==0, dk%4==0.
__global__ __launch_bounds__(256) void cvt_pad_kernel(const void* __restrict__ in,
                                                      bf16* __restrict__ out,
                                                      int rows, int sk, int dk,
                                                      const int* __restrict__ flagp) {
    int i = blockIdx.x * 256 + threadIdx.x;
    int g4 = dk >> 2;
    if (i >= rows * g4) return;
    int row = i / g4;
    int c = (i - row * g4) * 4;
    uint2 w;
    w.x = 0u; w.y = 0u;
    if (c < sk) {
        if (flagp[0]) {
            w = *(const uint2*)((const char*)in + ((size_t)row * sk + c) * 2);
        } else {
            const float* f = (const float*)((const char*)in + ((size_t)row * sk + c) * 4);
            union { bf16 t[4]; uint2 u; } pk;
            pk.t[0] = __float2bfloat16(f[0]);
            pk.t[1] = __float2bfloat16(f[1]);
            pk.t[2] = __float2bfloat16(f[2]);
            pk.t[3] = __float2bfloat16(f[3]);
            w = pk.u;
        }
    }
    *(uint2*)((char*)out + ((size_t)row * dk + c) * 2) = w;
}

// batched weight conversion: blockIdx.y = job
struct WJobs {
    const void* src[10];
    bf16* dst[10];
    int rows[10];
    int sk[10];
    int dk[10];
};
__global__ __launch_bounds__(256) void cvt_pad_multi(WJobs J, const int* __restrict__ flagp) {
    int j = blockIdx.y;
    int g4 = J.dk[j] >> 2;
    int tot = J.rows[j] * g4;
    int i = blockIdx.x * 256 + threadIdx.x;
    if (i >= tot) return;
    int row = i / g4;
    int c = (i - row * g4) * 4;
    int sk = J.sk[j];
    uint2 w;
    w.x = 0u; w.y = 0u;
    if (c < sk) {
        if (flagp[0]) {
            w = *(const uint2*)((const char*)J.src[j] + ((size_t)row * sk + c) * 2);
        } else {
            const float* f = (const float*)((const char*)J.src[j] + ((size_t)row * sk + c) * 4);
            union { bf16 t[4]; uint2 u; } pk;
            pk.t[0] = __float2bfloat16(f[0]);
            pk.t[1] = __float2bfloat16(f[1]);
            pk.t[2] = __float2bfloat16(f[2]);
            pk.t[3] = __float2bfloat16(f[3]);
            w = pk.u;
        }
    }
    *(uint2*)((char*)J.dst[j] + ((size_t)row * J.dk[j] + c) * 2) = w;
}

// batched small-vector f32 conversion: blockIdx.x = job
struct VJobs {
    const void* src[13];
    float* dst[13];
    int n[13];
};
__global__ __launch_bounds__(576) void cvt_f32_multi(VJobs J, const int* __restrict__ flagp) {
    int j = blockIdx.x;
    int c = threadIdx.x;
    if (c >= J.n[j]) return;
    float v;
    if (flagp[0]) v = __bfloat162float(((const bf16*)J.src[j])[c]);
    else v = ((const float*)J.src[j])[c];
    J.dst[j][c] = v;
}

__global__ __launch_bounds__(256) void fill_kernel(bf16* __restrict__ out, long long n) {
    long long i = (long long)blockIdx.x * 256 + threadIdx.x;
    if (i < n) out[i] = __float2bfloat16(1000.0f);
}

// ---------------- CSR build ----------------

__global__ __launch_bounds__(256) void count_kernel(const int* __restrict__ dst,
                                                    int* __restrict__ cnt) {
    int e = blockIdx.x * 256 + threadIdx.x;
    if (e < NE) atomicAdd(&cnt[dst[e]], 1);
}

// 3-phase device-wide exclusive scan over cnt[NN] (1024 elems per block).
#define SCAN_NB ((NN + 1023) / 1024)  // 98

__global__ __launch_bounds__(256) void scan_partial_kernel(const int* __restrict__ cnt,
                                                           int* __restrict__ bsum) {
    __shared__ int lds[256];
    int t = threadIdx.x;
    int base = blockIdx.x * 1024 + t * 4;
    int s = 0;
#pragma unroll
    for (int i = 0; i < 4; ++i) {
        int idx = base + i;
        if (idx < NN) s += cnt[idx];
    }
    lds[t] = s;
    __syncthreads();
    for (int h = 128; h > 0; h >>= 1) {
        if (t < h) lds[t] += lds[t + h];
        __syncthreads();
    }
    if (t == 0) bsum[blockIdx.x] = lds[0];
}

__global__ __launch_bounds__(128) void scan_bsum_kernel(int* __restrict__ bsum,
                                                        int* __restrict__ indptr) {
    __shared__ int lds[128];
    int t = threadIdx.x;
    int v = (t < SCAN_NB) ? bsum[t] : 0;
    lds[t] = v;
    __syncthreads();
    for (int off = 1; off < 128; off <<= 1) {
        int x = (t >= off) ? lds[t - off] : 0;
        __syncthreads();
        lds[t] += x;
        __syncthreads();
    }
    if (t < SCAN_NB) bsum[t] = lds[t] - v;  // exclusive
    if (t == 127) indptr[NN] = lds[127];
}

__global__ __launch_bounds__(256) void scan_apply_kernel(const int* __restrict__ cnt,
                                                         const int* __restrict__ bsum,
                                                         int* __restrict__ indptr,
                                                         int* __restrict__ cursor,
                                                         float* __restrict__ recip) {
    __shared__ int lds[256];
    int t = threadIdx.x;
    int base = blockIdx.x * 1024 + t * 4;
    int c[4];
    int s = 0;
#pragma unroll
    for (int i = 0; i < 4; ++i) {
        int idx = base + i;
        c[i] = (idx < NN) ? cnt[idx] : 0;
        s += c[i];
    }
    lds[t] = s;
    __syncthreads();
    for (int off = 1; off < 256; off <<= 1) {
        int x = (t >= off) ? lds[t - off] : 0;
        __syncthreads();
        lds[t] += x;
        __syncthreads();
    }
    int run = bsum[blockIdx.x] + lds[t] - s;  // exclusive prefix
#pragma unroll
    for (int i = 0; i < 4; ++i) {
        int idx = base + i;
        if (idx < NN) {
            indptr[idx] = run;
            cursor[idx] = run;
            recip[idx] = 1.0f / (float)(c[i] > 1 ? c[i] : 1);
            run += c[i];
        }
    }
}

__global__ __launch_bounds__(256) void scatter_kernel(const int* __restrict__ src,
                                                      const int* __restrict__ dst,
                                                      int* __restrict__ cursor,
                                                      int* __restrict__ csr) {
    int e = blockIdx.x * 256 + threadIdx.x;
    if (e < NE) {
        int d = dst[e];
        int p = atomicAdd(&cursor[d], 1);
        csr[p] = src[e];
    }
}

// ---------------- plain aggregation (layer-1 ADD path, no BN) ----------------
template <int D, int ADD>
__global__ __launch_bounds__(256) void aggv_kernel(const bf16* __restrict__ u,
                                                   const int* __restrict__ indptr,
                                                   const int* __restrict__ csr,
                                                   const float* __restrict__ recip,
                                                   bf16* __restrict__ out) {
    constexpr int TPR = D / 8;       // threads per node row
    constexpr int NPB = 256 / TPR;   // nodes per block
    const int tid = threadIdx.x;
    const int node = blockIdx.x * NPB + tid / TPR;
    if (node >= NN) return;
    const int c0 = (tid % TPR) * 8;
    const short* ub = (const short*)u + c0;
    const int j0 = indptr[node], j1 = indptr[node + 1];
    float acc[8];
#pragma unroll
    for (int t = 0; t < 8; ++t) acc[t] = 0.f;
    int j = j0;
    for (; j + 3 < j1; j += 4) {
        int s0 = csr[j], s1 = csr[j + 1], s2 = csr[j + 2], s3 = csr[j + 3];
        short8 v0 = *(const short8*)(ub + (size_t)s0 * D);
        short8 v1 = *(const short8*)(ub + (size_t)s1 * D);
        short8 v2 = *(const short8*)(ub + (size_t)s2 * D);
        short8 v3 = *(const short8*)(ub + (size_t)s3 * D);
#pragma unroll
        for (int t = 0; t < 8; ++t)
            acc[t] += (bf2f(v0[t]) + bf2f(v1[t])) + (bf2f(v2[t]) + bf2f(v3[t]));
    }
    for (; j < j1; ++j) {
        short8 v0 = *(const short8*)(ub + (size_t)csr[j] * D);
#pragma unroll
        for (int t = 0; t < 8; ++t) acc[t] += bf2f(v0[t]);
    }
    const float r = recip[node];
    size_t o = (size_t)node * D + c0;
    short8 w;
    if (ADD) {
        short8 prev = *(const short8*)((const short*)out + o);
#pragma unroll
        for (int t = 0; t < 8; ++t) w[t] = f2bf(acc[t] * r + bf2f(prev[t]));
    } else {
#pragma unroll
        for (int t = 0; t < 8; ++t) w[t] = f2bf(acc[t] * r);
    }
    *(short8*)((short*)out + o) = w;
}

// ---------------- fused BN-apply + aggregation ----------------
// raw: pre-BN gemm output. For its own node row, writes act = relu(raw*sc+sh).
// For the gather, applies BN+ReLU on the fly to each neighbor's raw row.
template <int D>
__global__ __launch_bounds__(256) void aggbn_kernel(const bf16* __restrict__ raw,
                                                    const int* __restrict__ indptr,
                                                    const int* __restrict__ csr,
                                                    const float* __restrict__ recip,
                                                    const float* __restrict__ scale,
                                                    const float* __restrict__ shift,
                                                    bf16* __restrict__ act,
                                                    bf16* __restrict__ agg) {
    constexpr int TPR = D / 8;
    constexpr int NPB = 256 / TPR;
    const int tid = threadIdx.x;
    const int node = blockIdx.x * NPB + tid / TPR;
    if (node >= NN) return;
    const int c0 = (tid % TPR) * 8;
    float sc[8], sh[8];
    *(float4*)&sc[0] = *(const float4*)&scale[c0];
    *(float4*)&sc[4] = *(const float4*)&scale[c0 + 4];
    *(float4*)&sh[0] = *(const float4*)&shift[c0];
    *(float4*)&sh[4] = *(const float4*)&shift[c0 + 4];
    const short* ub = (const short*)raw + c0;
    // own-row activation
    {
        short8 v = *(const short8*)(ub + (size_t)node * D);
        short8 w;
#pragma unroll
        for (int t = 0; t < 8; ++t) {
            float x = bf2f(v[t]) * sc[t] + sh[t];
            w[t] = f2bf(x > 0.f ? x : 0.f);
        }
        *(short8*)((short*)act + (size_t)node * D + c0) = w;
    }
    const int j0 = indptr[node], j1 = indptr[node + 1];
    float acc[8];
#pragma unroll
    for (int t = 0; t < 8; ++t) acc[t] = 0.f;
    int j = j0;
    for (; j + 3 < j1; j += 4) {
        int s0 = csr[j], s1 = csr[j + 1], s2 = csr[j + 2], s3 = csr[j + 3];
        short8 v0 = *(const short8*)(ub + (size_t)s0 * D);
        short8 v1 = *(const short8*)(ub + (size_t)s1 * D);
        short8 v2 = *(const short8*)(ub + (size_t)s2 * D);
        short8 v3 = *(const short8*)(ub + (size_t)s3 * D);
#pragma unroll
        for (int t = 0; t < 8; ++t) {
            float x0 = fmaxf(bf2f(v0[t]) * sc[t] + sh[t], 0.f);
            float x1 = fmaxf(bf2f(v1[t]) * sc[t] + sh[t], 0.f);
            float x2 = fmaxf(bf2f(v2[t]) * sc[t] + sh[t], 0.f);
            float x3 = fmaxf(bf2f(v3[t]) * sc[t] + sh[t], 0.f);
            acc[t] += (x0 + x1) + (x2 + x3);
        }
    }
    for (; j < j1; ++j) {
        short8 v0 = *(const short8*)(ub + (size_t)csr[j] * D);
#pragma unroll
        for (int t = 0; t < 8; ++t)
            acc[t] += fmaxf(bf2f(v0[t]) * sc[t] + sh[t], 0.f);
    }
    const float r = recip[node];
    size_t o = (size_t)node * D + c0;
    short8 w;
#pragma unroll
    for (int t = 0; t < 8; ++t) w[t] = f2bf(acc[t] * r);
    *(short8*)((short*)agg + o) = w;
}

// ---------------- bf16 MFMA GEMM:  out = A1@W1^T (+ A2@W2^T) (+ bias) ----------------
// 256x64 tile, BK=64, double-buffered LDS (80KB): stage(t+1) issued before
// compute(t); single __syncthreads per K-step (drains vmcnt before s_barrier
// on gfx950, so it certifies both "prefetch landed" and "buffer free").
// Column-split output: cols [0,Nsplit) -> outB, cols [Nsplit,N) -> outB2.
__device__ __forceinline__ void gld_lds16(const void* g, void* l) {
    __builtin_amdgcn_global_load_lds(
        (const __attribute__((address_space(1))) unsigned int*)g,
        (__attribute__((address_space(3))) unsigned int*)l, 16, 0, 0);
}

__global__ __launch_bounds__(256) void gemm_kernel(
    const bf16* __restrict__ A1, const bf16* __restrict__ W1, int K1,
    const bf16* __restrict__ A2, const bf16* __restrict__ W2, int K2,
    const float* __restrict__ bias,
    bf16* __restrict__ outB, bf16* __restrict__ outB2, int Nsplit,
    void* __restrict__ outFinal,
    float* __restrict__ statp,
    const int* __restrict__ flagp,
    int M, int N) {
    // 80KB: two 40KB buffers (sA 32KB + sW 8KB each). Epilogue reuses 64KB.
    __shared__ alignas(16) char smem[81920];

    const int tid = threadIdx.x;
    const int lane = tid & 63, wv = tid >> 6;
    const int lrow = lane & 15, lq = lane >> 4;

    // XCD-aware bijective swizzle (T1, m204 formula)
    const int nwg = gridDim.x * gridDim.y;
    const int flat = blockIdx.y * gridDim.x + blockIdx.x;
    const int xcd = flat & 7;
    const int rest = flat >> 3;
    const int q = nwg >> 3, r = nwg & 7;
    const int chunk = (xcd < r) ? xcd * (q + 1) : r * (q + 1) + (xcd - r) * q;
    const int newid = chunk + rest;
    const int n0 = (newid % gridDim.x) * 64;
    const int m0 = (newid / gridDim.x) * 256;

    const int isbf = flagp[0];

    f32x4 acc[4][4];
#pragma unroll
    for (int a = 0; a < 4; ++a)
#pragma unroll
        for (int b = 0; b < 4; ++b) acc[a][b] = (f32x4){0.f, 0.f, 0.f, 0.f};

    const int sr = tid >> 3;
    const int scb = (tid & 7) << 4;

    const int nt1 = K1 >> 6;
    const int nt2 = K2 >> 6;
    const int nt = nt1 + nt2;

    auto stage = [&](int t, int b) {
        const bf16* Ap;
        const bf16* Wp;
        int K, k0;
        if (t < nt1) { Ap = A1; Wp = W1; K = K1; k0 = t << 6; }
        else { Ap = A2; Wp = W2; K = K2; k0 = (t - nt1) << 6; }
        char* bA = smem + b * 40960;
        char* bW = bA + 32768;
#pragma unroll
        for (int i = 0; i < 8; ++i) {
            int row = i * 32 + sr;
            int gr = m0 + row;
            if (gr >= M) gr = M - 1;  // clamp tail (epilogue guards writes)
            const char* g = (const char*)Ap + ((size_t)gr * K + k0) * 2 +
                            (scb ^ ((row & 7) << 4));
            gld_lds16(g, bA + row * 128 + scb);
        }
#pragma unroll
        for (int i = 0; i < 2; ++i) {
            int row = i * 32 + sr;
            const char* g = (const char*)Wp + ((size_t)(n0 + row) * K + k0) * 2 +
                            (scb ^ ((row & 7) << 4));
            gld_lds16(g, bW + row * 128 + scb);
        }
    };

    stage(0, 0);
    __syncthreads();  // drains vmcnt(0) -> buf0 ready
    int cur = 0;
#pragma unroll 1
    for (int t = 0; t < nt; ++t) {
        if (t + 1 < nt) stage(t + 1, cur ^ 1);  // prefetch overlaps compute below
        const char* sA = smem + cur * 40960;
        const char* sW = sA + 32768;
#pragma unroll
        for (int kh = 0; kh < 2; ++kh) {
            short8 a[4], b[4];
            const int cb = kh * 64 + lq * 16;
#pragma unroll
            for (int mi = 0; mi < 4; ++mi) {
                int row = wv * 64 + mi * 16 + lrow;
                a[mi] = *(const short8*)(sA + row * 128 + (cb ^ ((row & 7) << 4)));
            }
#pragma unroll
            for (int ni = 0; ni < 4; ++ni) {
                int row = ni * 16 + lrow;
                b[ni] = *(const short8*)(sW + row * 128 + (cb ^ ((row & 7) << 4)));
            }
#pragma unroll
            for (int mi = 0; mi < 4; ++mi)
#pragma unroll
                for (int ni = 0; ni < 4; ++ni)
                    acc[mi][ni] = __builtin_amdgcn_mfma_f32_16x16x32_bf16(
                        a[mi], b[ni], acc[mi][ni], 0, 0, 0);
        }
        __syncthreads();  // prefetch landed + all waves done reading cur
        cur ^= 1;
    }

    // ---- epilogue ----
    // C/D layout: grow = m0 + wv*64 + mi*16 + lq*4 + r, gcol = n0 + ni*16 + lrow
    if (statp) {
#pragma unroll
        for (int ni = 0; ni < 4; ++ni) {
            int gcol = n0 + ni * 16 + lrow;
            float bv = bias ? bias[gcol] : 0.f;
            float s = 0.f, q2 = 0.f;
#pragma unroll
            for (int mi = 0; mi < 4; ++mi) {
#pragma unroll
                for (int r2 = 0; r2 < 4; ++r2) {
                    int grow = m0 + wv * 64 + mi * 16 + lq * 4 + r2;
                    if (grow < M) {
                        float v = acc[mi][ni][r2] + bv;
                        s += v;
                        q2 += v * v;
                    }
                }
            }
            s += __shfl_xor(s, 16, 64);
            s += __shfl_xor(s, 32, 64);
            q2 += __shfl_xor(q2, 16, 64);
            q2 += __shfl_xor(q2, 32, 64);
            if (lq == 0) {
                atomicAdd(&statp[gcol], s);
                atomicAdd(&statp[N + gcol], q2);
            }
        }
    }
    // LDS-transpose store (loop ended with a barrier; smem free to reuse)
    const bool f32out = (outFinal != nullptr) && !isbf;
    if (!f32out) {
        // bf16 output: one round, 256x64 bf16 = 32KB
        bf16* dst = outB ? outB : (bf16*)outFinal;
        short* sc = (short*)smem;
#pragma unroll
        for (int ni = 0; ni < 4; ++ni) {
            float bv = bias ? bias[n0 + ni * 16 + lrow] : 0.f;
#pragma unroll
            for (int mi = 0; mi < 4; ++mi) {
                int rl = wv * 64 + mi * 16 + lq * 4;
#pragma unroll
                for (int r2 = 0; r2 < 4; ++r2)
                    sc[(rl + r2) * 64 + ni * 16 + lrow] = f2bf(acc[mi][ni][r2] + bv);
            }
        }
        __syncthreads();
#pragma unroll
        for (int i = 0; i < 8; ++i) {
            int f8 = tid + i * 256;       // short8 index, 8 per row
            int rowl = f8 >> 3;
            int col0 = (f8 & 7) * 8;
            int grow = m0 + rowl;
            int gcol = n0 + col0;
            if (grow < M) {
                short8 v = ((const short8*)smem)[f8];
                if (gcol < Nsplit)
                    *(short8*)((short*)dst + (size_t)grow * Nsplit + gcol) = v;
                else
                    *(short8*)((short*)outB2 + (size_t)grow * (N - Nsplit) +
                               (gcol - Nsplit)) = v;
            }
        }
    } else {
        // fp32 output: single round, 256x64 f32 = 64KB (fits in 80KB)
        float* dst = (float*)outFinal;
        float* sf = (float*)smem;
#pragma unroll
        for (int ni = 0; ni < 4; ++ni) {
            float bv = bias ? bias[n0 + ni * 16 + lrow] : 0.f;
#pragma unroll
            for (int mi = 0; mi < 4; ++mi) {
                int rl = wv * 64 + mi * 16 + lq * 4;
#pragma unroll
                for (int r2 = 0; r2 < 4; ++r2)
                    sf[(rl + r2) * 64 + ni * 16 + lrow] = acc[mi][ni][r2] + bv;
            }
        }
        __syncthreads();
#pragma unroll
        for (int i = 0; i < 16; ++i) {
            int f4 = tid + i * 256;   // float4 index, 16 per row
            int rowl = f4 >> 4;
            int col0 = (f4 & 15) * 4;
            int grow = m0 + rowl;
            if (grow < M)
                *(float4*)(dst + (size_t)grow * N + n0 + col0) =
                    ((const float4*)smem)[f4];
        }
    }
}

// ---------------- BatchNorm (stats for layer 1 only; finalize shared) ----------------

__global__ __launch_bounds__(256) void bn_stats_kernel(const bf16* __restrict__ C,
                                                       int ldN,
                                                       float* __restrict__ stats) {
    int N = 1 << ldN;
    int tid = threadIdx.x;
    int c = tid & (N - 1);
    int rsub = tid >> ldN;
    int rstep = 256 >> ldN;
    int r0 = blockIdx.x * 64;
    float s = 0.f, q = 0.f;
    for (int r = r0 + rsub; r < r0 + 64; r += rstep) {
        if (r < NN) {
            float v = __bfloat162float(C[(size_t)r * N + c]);
            s += v;
            q += v * v;
        }
    }
    __shared__ float ls[256], lq[256];
    ls[tid] = s;
    lq[tid] = q;
    __syncthreads();
    for (int half = rstep >> 1; half > 0; half >>= 1) {
        if (rsub < half) {
            ls[tid] += ls[tid + half * N];
            lq[tid] += lq[tid + half * N];
        }
        __syncthreads();
    }
    if (rsub == 0) {
        atomicAdd(&stats[c], ls[tid]);
        atomicAdd(&stats[N + c], lq[tid]);
    }
}

__global__ __launch_bounds__(256) void bn_finalize_kernel(const float* __restrict__ stats,
                                                          const float* __restrict__ g,
                                                          const float* __restrict__ be,
                                                          int N,
                                                          float* __restrict__ scale,
                                                          float* __restrict__ shift) {
    int c = threadIdx.x;
    if (c >= N) return;
    float mean = stats[c] * (1.0f / NN);
    float var = stats[N + c] * (1.0f / NN) - mean * mean;
    var = fmaxf(var, 0.f);
    float sc = g[c] * rsqrtf(var + 1e-5f);
    scale[c] = sc;
    shift[c] = be[c] - mean * sc;
}

// ---------------- host launch ----------------

extern "C" void kernel_launch(void* const* d_in, const int* in_sizes, int n_in,
                              void* d_out, int out_size, void* d_ws, size_t ws_size,
                              hipStream_t stream) {
    const void* x_raw = d_in[0];
    const int* ei = (const int*)d_in[1];
    const int* src = ei;
    const int* dst = ei + NE;

    char* w = (char*)d_ws;
    size_t off = 0;
    auto alloc = [&](size_t bytes) {
        void* p = w + off;
        off = (off + bytes + 255) & ~(size_t)255;
        return p;
    };
    int* flags = (int*)alloc(256);
    int* cnt = (int*)alloc((size_t)NN * 4);
    int* indptr = (int*)alloc((size_t)(NN + 1) * 4);
    int* cursor = (int*)alloc((size_t)NN * 4);
    float* recip = (float*)alloc((size_t)NN * 4);
    int* csr = (int*)alloc((size_t)NE * 4);
    int* bsum = (int*)alloc((size_t)SCAN_NB * 4);
    const int KDIM[5] = {196, 64, 128, 256, 256};   // source K
    const int KPAD[5] = {256, 64, 128, 256, 256};   // padded K (row stride)
    const int NDIM[5] = {64, 128, 256, 256, 576};
    bf16 *Wlb[5], *Wrb[5];
    float *bf_[5], *gf[4], *bef[4];
    for (int i = 0; i < 5; ++i) {
        // Wlb[i] and Wrb[i] contiguous: layer-1 fused gemm uses [Wl1;Wr1] as 128x256.
        Wlb[i] = (bf16*)alloc((size_t)KPAD[i] * NDIM[i] * 2);
        Wrb[i] = (bf16*)alloc((size_t)KPAD[i] * NDIM[i] * 2);
        bf_[i] = (float*)alloc((size_t)NDIM[i] * 4);
    }
    for (int i = 0; i < 4; ++i) {
        gf[i] = (float*)alloc((size_t)NDIM[i] * 4);
        bef[i] = (float*)alloc((size_t)NDIM[i] * 4);
    }
    float* bias1cat = (float*)alloc(128 * 4);  // [0..63]=0, [64..127]=b1
    float* stats = (float*)alloc(1408 * 4);
    float* scale = (float*)alloc(256 * 4);
    float* shift = (float*)alloc(256 * 4);
    float *s1 = stats, *s2 = stats + 128, *s3 = stats + 384, *s4 = stats + 896;
    // big slots: raw always in S1, act in S2, agg/x in aggb
    bf16* aggb = (bf16*)alloc((size_t)NN * 256 * 2);
    bf16* S1 = (bf16*)alloc((size_t)NN * 256 * 2);
    bf16* S2 = (bf16*)alloc((size_t)NN * 256 * 2);
    bf16* xb = aggb;
    bf16* u1 = S2;

    if (off > ws_size) {
        long long n = (long long)NN * 576;
        fill_kernel<<<(int)((n + 255) / 256), 256, 0, stream>>>((bf16*)d_out, n);
        return;
    }

    hipMemsetAsync(cnt, 0, (size_t)NN * 4, stream);
    hipMemsetAsync(stats, 0, 1408 * 4, stream);
    hipMemsetAsync(bias1cat, 0, 64 * 4, stream);

    detect_kernel<<<1, 64, 0, stream>>>((const unsigned int*)x_raw, flags);

    // canonicalize inputs: x (large, own launch) + batched weights + batched vectors
    {
        int totx = NN * (KPAD[0] >> 2);
        cvt_pad_kernel<<<(totx + 255) / 256, 256, 0, stream>>>(x_raw, xb, NN, 196, 256, flags);

        WJobs wj;
        int maxb = 0;
        for (int i = 0; i < 5; ++i) {
            wj.src[2 * i] = d_in[2 + 3 * i];
            wj.dst[2 * i] = Wlb[i];
            wj.src[2 * i + 1] = d_in[3 + 3 * i];
            wj.dst[2 * i + 1] = Wrb[i];
            wj.rows[2 * i] = wj.rows[2 * i + 1] = NDIM[i];
            wj.sk[2 * i] = wj.sk[2 * i + 1] = KDIM[i];
            wj.dk[2 * i] = wj.dk[2 * i + 1] = KPAD[i];
            int nb = (NDIM[i] * (KPAD[i] >> 2) + 255) / 256;
            if (nb > maxb) maxb = nb;
        }
        cvt_pad_multi<<<dim3(maxb, 10), 256, 0, stream>>>(wj, flags);

        VJobs vj;
        vj.src[0] = d_in[4];  vj.dst[0] = bias1cat + 64; vj.n[0] = 64;  // b1
        for (int i = 1; i < 5; ++i) {
            vj.src[i] = d_in[4 + 3 * i];
            vj.dst[i] = bf_[i];
            vj.n[i] = NDIM[i];
        }
        for (int i = 0; i < 4; ++i) {
            vj.src[5 + i] = d_in[17 + 2 * i];
            vj.dst[5 + i] = gf[i];
            vj.n[5 + i] = NDIM[i];
            vj.src[9 + i] = d_in[18 + 2 * i];
            vj.dst[9 + i] = bef[i];
            vj.n[9 + i] = NDIM[i];
        }
        cvt_f32_multi<<<13, 576, 0, stream>>>(vj, flags);
    }

    count_kernel<<<(NE + 255) / 256, 256, 0, stream>>>(dst, cnt);
    scan_partial_kernel<<<SCAN_NB, 256, 0, stream>>>(cnt, bsum);
    scan_bsum_kernel<<<1, 128, 0, stream>>>(bsum, indptr);
    scan_apply_kernel<<<SCAN_NB, 256, 0, stream>>>(cnt, bsum, indptr, cursor, recip);
    scatter_kernel<<<(NE + 255) / 256, 256, 0, stream>>>(src, dst, cursor, csr);

    const int GM = (NN + 63) / 64;     // bn_stats grid (layer 1 only)
    const int GY = (NN + 255) / 256;   // gemm M-tiles (391)

    // ---- Layer 1: fused dual-output gemm: Wcat=[Wl1;Wr1] (128x256 contiguous),
    // cols 0-63 -> u1 (no bias), cols 64-127 -> S1 (+b1). Aggregate AFTER lin_l.
    gemm_kernel<<<dim3(2, GY), 256, 0, stream>>>(xb, Wlb[0], 256, nullptr, nullptr, 0,
                                                 bias1cat, u1, S1, 64,
                                                 nullptr, nullptr, flags, NN, 128);
    aggv_kernel<64, 1><<<NN / 32, 256, 0, stream>>>(u1, indptr, csr, recip, S1);
    bn_stats_kernel<<<GM, 256, 0, stream>>>(S1, 6, s1);
    bn_finalize_kernel<<<1, 256, 0, stream>>>(s1, gf[0], bef[0], 64, scale, shift);

    // ---- Layer 2: fused bn1-apply + agg (raw1=S1 -> act1=S2, agg1=aggb)
    aggbn_kernel<64><<<NN / 32, 256, 0, stream>>>(S1, indptr, csr, recip, scale, shift,
                                                  S2, aggb);
    gemm_kernel<<<dim3(2, GY), 256, 0, stream>>>(aggb, Wlb[1], 64, S2, Wrb[1], 64,
                                                 bf_[1], S1, nullptr, 128,
                                                 nullptr, s2, flags, NN, 128);
    bn_finalize_kernel<<<1, 256, 0, stream>>>(s2, gf[1], bef[1], 128, scale, shift);

    // ---- Layer 3: fused bn2-apply + agg (raw2=S1 -> act2=S2, agg2=aggb)
    aggbn_kernel<128><<<NN / 16, 256, 0, stream>>>(S1, indptr, csr, recip, scale, shift,
                                                   S2, aggb);
    gemm_kernel<<<dim3(4, GY), 256, 0, stream>>>(aggb, Wlb[2], 128, S2, Wrb[2], 128,
                                                 bf_[2], S1, nullptr, 256,
                                                 nullptr, s3, flags, NN, 256);
    bn_finalize_kernel<<<1, 256, 0, stream>>>(s3, gf[2], bef[2], 256, scale, shift);

    // ---- Layer 4: fused bn3-apply + agg (raw3=S1 -> act3=S2, agg3=aggb)
    aggbn_kernel<256><<<NN / 8, 256, 0, stream>>>(S1, indptr, csr, recip, scale, shift,
                                                  S2, aggb);
    gemm_kernel<<<dim3(4, GY), 256, 0, stream>>>(aggb, Wlb[3], 256, S2, Wrb[3], 256,
                                                 bf_[3], S1, nullptr, 256,
                                                 nullptr, s4, flags, NN, 256);
    bn_finalize_kernel<<<1, 256, 0, stream>>>(s4, gf[3], bef[3], 256, scale, shift);

    // ---- Layer 5: fused bn4-apply + agg, then final gemm -> d_out
    aggbn_kernel<256><<<NN / 8, 256, 0, stream>>>(S1, indptr, csr, recip, scale, shift,
                                                  S2, aggb);
    gemm_kernel<<<dim3(9, GY), 256, 0, stream>>>(aggb, Wlb[4], 256, S2, Wrb[4], 256,
                                                 bf_[4], nullptr, nullptr, 576,
                                                 d_out, nullptr, flags, NN, 576);
}